// Round 10
// baseline (591.616 us; speedup 1.0000x reference)
//
#include <hip/hip_runtime.h>
#include <math.h>

#define HW   4096
#define NCH  256
#define NB   4

constexpr float TEMP  = (float)(0.0001 * 5.0);
constexpr float INV_T = 1.0f / TEMP;
constexpr float EPSN  = 2.220446049250313e-16f;

typedef __attribute__((ext_vector_type(8))) _Float16 f16x8;
typedef __attribute__((ext_vector_type(4))) _Float16 f16x4;
typedef __attribute__((ext_vector_type(4))) float    f32x4;

// ---------------- workspace layout (in floats) ----------------
constexpr size_t OFF_YT    = 0;                                 // yf16: NB*HW*NCH f16
constexpr size_t OFF_YI    = OFF_YT    + (size_t)NB*HW*NCH;     // NB*3*HW
constexpr size_t OFF_MEAN  = OFF_YI    + (size_t)NB*3*HW;       // 2*NB*NCH
constexpr size_t OFF_RNORM = OFF_MEAN  + (size_t)2*NB*NCH;      // 2*NB*HW
constexpr size_t OFF_NSQP  = OFF_RNORM + (size_t)2*NB*HW;       // 2*NB*8*HW
// Pb region (was f32 f): two f16 [HW][HW] arrays = 64 MB total
constexpr size_t OFF_PB    = OFF_NSQP  + (size_t)2*NB*8*HW;     // HW*HW floats
constexpr size_t OFF_YP    = OFF_PB    + (size_t)HW*HW;         // 8*NCH*HW floats region
// rowp/colp ALIAS the yp region: consumed by combine before gemm_y writes yph
constexpr size_t OFF_ROWP  = OFF_YP;                            // [32 ntile][7][HW]
constexpr size_t OFF_COLP  = OFF_YP + (size_t)32*7*HW;          // [32 mtile][2][HW]
constexpr size_t OFF_RMAX  = OFF_YP    + (size_t)8*NCH*HW;
constexpr size_t OFF_RSUM  = OFF_RMAX  + HW;
constexpr size_t OFF_CMAX  = OFF_RSUM  + HW;
constexpr size_t OFF_CSUM  = OFF_CMAX  + HW;
constexpr size_t OFF_RMB   = OFF_CSUM  + HW;                // [32 ntile][HW m]
constexpr size_t OFF_CMB   = OFF_RMB   + (size_t)32*HW;     // [32 mtile][HW n]
constexpr size_t OFF_COORD = OFF_CMB   + (size_t)32*HW;     // NB*2*HW
constexpr size_t OFF_ATTN  = OFF_COORD + (size_t)NB*2*HW;   // NB*HW*3
constexpr size_t OFF_CYC   = OFF_ATTN  + (size_t)NB*HW*3;   // NB*3*HW
constexpr size_t OFF_CYCP  = OFF_CYC   + (size_t)NB*3*HW;   // 32*3*HW
constexpr size_t OFF_LOSSP = OFF_CYCP  + (size_t)32*3*HW;   // 1024
constexpr size_t OFF_F16   = OFF_LOSSP + 1024;              // 4 * 524288 floats

// ---------------- output layout (floats) ----------------
constexpr size_t OUT_Y    = 0;
constexpr size_t OUT_FLOW = (size_t)NB*NCH*HW;
constexpr size_t OUT_IMG  = OUT_FLOW + (size_t)NB*2*256*256;
constexpr size_t OUT_CYCO = OUT_IMG  + (size_t)NB*3*256*256;
constexpr size_t OUT_LOSS = OUT_CYCO + (size_t)NB*3*256*256;

__device__ __forceinline__ void gload16(const void* g, void* l) {
    __builtin_amdgcn_global_load_lds(
        (const __attribute__((address_space(1))) unsigned int*)g,
        (__attribute__((address_space(3))) unsigned int*)l, 16, 0, 0);
}

__global__ void mean_kernel(const float* __restrict__ xf, const float* __restrict__ yf,
                            float* __restrict__ means) {
    const float* src = (blockIdx.y == 0 ? xf : yf) + (size_t)blockIdx.x * HW;
    float s = 0.f;
    for (int i = threadIdx.x; i < HW; i += 256) s += src[i];
    __shared__ float red[256];
    red[threadIdx.x] = s; __syncthreads();
    for (int st = 128; st > 0; st >>= 1) {
        if (threadIdx.x < st) red[threadIdx.x] += red[threadIdx.x + st];
        __syncthreads();
    }
    if (threadIdx.x == 0) means[blockIdx.y * (NB*NCH) + blockIdx.x] = red[0] * (1.0f / HW);
}

__global__ void nsq_partial_kernel(const float* __restrict__ xf, const float* __restrict__ yf,
                                   const float* __restrict__ means, float* __restrict__ part) {
    int t = blockIdx.z >> 2, b = blockIdx.z & 3;
    int m = blockIdx.x * 256 + threadIdx.x;
    int c0 = blockIdx.y * 32;
    const float* src = (t == 0 ? xf : yf) + (size_t)b * NCH * HW;
    const float* mn = means + t * (NB*NCH) + b * NCH;
    float acc = 0.f;
    for (int c = c0; c < c0 + 32; ++c) {
        float v = src[(size_t)c * HW + m] - mn[c];
        acc += v * v;
    }
    part[(((size_t)t*NB + b) * 8 + blockIdx.y) * HW + m] = acc;
}

__global__ void nsq_combine_kernel(const float* __restrict__ part, float* __restrict__ rnorms) {
    int t = blockIdx.y >> 2, b = blockIdx.y & 3;
    int m = blockIdx.x * 256 + threadIdx.x;
    const float* p = part + ((size_t)t*NB + b) * 8 * HW + m;
    float s = 0.f;
    for (int k = 0; k < 8; ++k) s += p[(size_t)k * HW];
    rnorms[((size_t)t*NB + b) * HW + m] = 1.0f / (sqrtf(s) + EPSN);
}

__global__ void ycast_kernel(const float* __restrict__ yf, _Float16* __restrict__ yf16) {
    size_t i = ((size_t)blockIdx.x * 256 + threadIdx.x) * 8;
    const float4* s = (const float4*)(yf + i);
    float4 v0 = s[0], v1 = s[1];
    f16x8 o;
    o[0]=(_Float16)v0.x; o[1]=(_Float16)v0.y; o[2]=(_Float16)v0.z; o[3]=(_Float16)v0.w;
    o[4]=(_Float16)v1.x; o[5]=(_Float16)v1.y; o[6]=(_Float16)v1.z; o[7]=(_Float16)v1.w;
    *(f16x8*)(yf16 + i) = o;
}

__global__ void prep_kernel(const float* __restrict__ xf, const float* __restrict__ yf,
                            const float* __restrict__ means,
                            _Float16* __restrict__ th, _Float16* __restrict__ tl,
                            _Float16* __restrict__ ph, _Float16* __restrict__ pl, int b) {
    __shared__ float tile[32][33];
    int t = blockIdx.z;
    int c0 = blockIdx.x * 32, m0 = blockIdx.y * 32;
    const float* src = (t == 0 ? xf : yf) + (size_t)b * NCH * HW;
    const float* mn  = means + t * (NB*NCH) + b * NCH;
    int tx = threadIdx.x & 31, ty = threadIdx.x >> 5;
    for (int i = ty; i < 32; i += 8)
        tile[i][tx] = src[(size_t)(c0 + i) * HW + m0 + tx] - mn[c0 + i];
    __syncthreads();
    _Float16* H = (t == 0 ? th : ph);
    _Float16* L = (t == 0 ? tl : pl);
    for (int i = ty; i < 32; i += 8) {
        float v = tile[tx][i];
        _Float16 h = (_Float16)v;
        _Float16 l = (_Float16)(v - (float)h);
        H[(size_t)(m0 + i)*NCH + c0 + tx] = h;
        L[(size_t)(m0 + i)*NCH + c0 + tx] = l;
    }
}

__global__ void avgpool_kernel(const float* __restrict__ yimg, float* __restrict__ yi) {
    size_t idx = (size_t)blockIdx.x * 256 + threadIdx.x;
    int m  = (int)(idx & (HW - 1));
    int bc = (int)(idx >> 12);
    int h = m >> 6, w = m & 63;
    const float* p = yimg + (size_t)bc * 65536 + (size_t)(h*4) * 256 + w*4;
    float s = 0.f;
    #pragma unroll
    for (int dy = 0; dy < 4; ++dy) {
        #pragma unroll
        for (int dx = 0; dx < 4; ++dx) s += p[dy*256 + dx];
    }
    yi[idx] = s * (1.0f/16.0f);
}

// f^T accumulator GEMM: 128x128 tile, 4 waves, BK=32, 2-phase dbuf LDS.
// Outputs: Pb_row = f16 exp((f-rmb)/T), Pb_col = f16 exp((f-cmb)/T)  (both [m][n]),
// rmb/cmb block maxima, and row/col softmax partial stats. f32 f never materialized.
__global__ __launch_bounds__(256) void gemm_f_kernel(
        const _Float16* __restrict__ th, const _Float16* __restrict__ tl,
        const _Float16* __restrict__ ph, const _Float16* __restrict__ pl,
        const float* __restrict__ rnorms, const float* __restrict__ yi,
        _Float16* __restrict__ Pbr, _Float16* __restrict__ Pbc,
        float* __restrict__ rowp, float* __restrict__ colp,
        float* __restrict__ rmb, float* __restrict__ cmb, int b) {
    __shared__ char lds[2][4][8192];
    int tid  = threadIdx.x;
    int lane = tid & 63;
    int w = tid >> 6, wm = w >> 1, wn = w & 1;   // wm: n-block, wn: m-block
    int m0 = blockIdx.y * 128, n0 = blockIdx.x * 128;

    int o0 = tid * 16, o1 = o0 + 4096;
    int r0 = o0 >> 6, s0 = (o0 >> 4) & 3, g0 = s0 ^ ((r0 >> 1) & 3);
    int r1 = o1 >> 6, s1 = (o1 >> 4) & 3, g1 = s1 ^ ((r1 >> 1) & 3);
    size_t ga0 = (size_t)(n0 + r0)*NCH + g0*8;
    size_t ga1 = (size_t)(n0 + r1)*NCH + g1*8;
    size_t gb0 = (size_t)(m0 + r0)*NCH + g0*8;
    size_t gb1 = (size_t)(m0 + r1)*NCH + g1*8;

    int fra = wm*64 + (lane & 15);
    int frb = wn*64 + (lane & 15);
    int ks  = lane >> 4;

    auto STAGE = [&](int buf, int k0) {
        gload16(ph + ga0 + k0, &lds[buf][0][o0]);
        gload16(ph + ga1 + k0, &lds[buf][0][o1]);
        gload16(pl + ga0 + k0, &lds[buf][1][o0]);
        gload16(pl + ga1 + k0, &lds[buf][1][o1]);
        gload16(th + gb0 + k0, &lds[buf][2][o0]);
        gload16(th + gb1 + k0, &lds[buf][2][o1]);
        gload16(tl + gb0 + k0, &lds[buf][3][o0]);
        gload16(tl + gb1 + k0, &lds[buf][3][o1]);
    };

    f32x4 acc[4][4];
    #pragma unroll
    for (int i = 0; i < 4; ++i)
        #pragma unroll
        for (int j = 0; j < 4; ++j) acc[i][j] = (f32x4){0.f, 0.f, 0.f, 0.f};

    STAGE(0, 0);
    __syncthreads();
    int cur = 0;
    for (int kt = 0; kt < 8; ++kt) {
        if (kt < 7) STAGE(cur ^ 1, (kt + 1) * 32);

        f16x8 ah[4], al[4], bh[4], bl[4];
        #pragma unroll
        for (int i = 0; i < 4; ++i) {
            int rowa = fra + i*16;
            int offa = rowa*64 + ((ks ^ ((rowa >> 1) & 3)) << 4);
            ah[i] = *(const f16x8*)&lds[cur][0][offa];
            al[i] = *(const f16x8*)&lds[cur][1][offa];
            int rowb = frb + i*16;
            int offb = rowb*64 + ((ks ^ ((rowb >> 1) & 3)) << 4);
            bh[i] = *(const f16x8*)&lds[cur][2][offb];
            bl[i] = *(const f16x8*)&lds[cur][3][offb];
        }
        #pragma unroll
        for (int i = 0; i < 4; ++i)
            #pragma unroll
            for (int j = 0; j < 4; ++j) {
                acc[i][j] = __builtin_amdgcn_mfma_f32_16x16x32_f16(ah[i], bh[j], acc[i][j], 0, 0, 0);
                acc[i][j] = __builtin_amdgcn_mfma_f32_16x16x32_f16(ah[i], bl[j], acc[i][j], 0, 0, 0);
                acc[i][j] = __builtin_amdgcn_mfma_f32_16x16x32_f16(al[i], bh[j], acc[i][j], 0, 0, 0);
            }
        __syncthreads();
        cur ^= 1;
    }

    // ---- scale in place: f[m][n] = accT * rnx[m] * rny[n] ----
    const float* rnx = rnorms + (size_t)b * HW;
    const float* rny = rnorms + (size_t)(NB + b) * HW;
    int mg[4];  float rxv[4];
    #pragma unroll
    for (int j = 0; j < 4; ++j) {
        mg[j] = m0 + wn*64 + j*16 + (lane & 15);
        rxv[j] = rnx[mg[j]];
    }
    int nl0 = wm*64 + (lane >> 4)*4;
    #pragma unroll
    for (int i = 0; i < 4; ++i)
        #pragma unroll
        for (int r = 0; r < 4; ++r) {
            float ry = rny[n0 + nl0 + i*16 + r];
            #pragma unroll
            for (int j = 0; j < 4; ++j) acc[i][j][r] *= rxv[j] * ry;
        }

    // ---- stats + Pb stores ----
    float* S     = (float*)&lds[0][0][0];
    float* rowm  = S;          // [2 wm][128 m]
    float* sums6 = S + 256;    // [2 wm][128 m][6]
    float* colm  = S + 1792;   // [2 wn][128 n]
    float* colsm = S + 2048;   // [2 wn][128 n]

    // phase A: per-wave maxes
    #pragma unroll
    for (int j = 0; j < 4; ++j) {
        float v = acc[0][j][0];
        #pragma unroll
        for (int i = 0; i < 4; ++i)
            #pragma unroll
            for (int r = 0; r < 4; ++r) v = fmaxf(v, acc[i][j][r]);
        v = fmaxf(v, __shfl_xor(v, 16));
        v = fmaxf(v, __shfl_xor(v, 32));
        if ((lane >> 4) == 0) rowm[wm*128 + wn*64 + j*16 + lane] = v;
    }
    #pragma unroll
    for (int i = 0; i < 4; ++i)
        #pragma unroll
        for (int r = 0; r < 4; ++r) {
            float v = fmaxf(fmaxf(acc[i][0][r], acc[i][1][r]),
                            fmaxf(acc[i][2][r], acc[i][3][r]));
            #pragma unroll
            for (int d = 1; d < 16; d <<= 1) v = fmaxf(v, __shfl_xor(v, d));
            if ((lane & 15) == 0) colm[wn*128 + wm*64 + i*16 + (lane >> 4)*4 + r] = v;
        }
    __syncthreads();

    // phase B: exp sums vs block maxes, plus Pb_row / Pb_col f16 stores
    float bm[4];
    #pragma unroll
    for (int j = 0; j < 4; ++j) {
        int ml = wn*64 + j*16 + (lane & 15);
        bm[j] = fmaxf(rowm[ml], rowm[128 + ml]);
    }
    float a6[4][6];
    #pragma unroll
    for (int j = 0; j < 4; ++j)
        #pragma unroll
        for (int q = 0; q < 6; ++q) a6[j][q] = 0.f;
    const float* yib = yi + (size_t)b * 3 * HW;
    #pragma unroll
    for (int i = 0; i < 4; ++i) {
        float er[4][4], ec[4][4];   // [r][j]
        #pragma unroll
        for (int r = 0; r < 4; ++r) {
            int nl = nl0 + i*16 + r;
            int ng = n0 + nl;
            float xc = (float)(ng & 63), yc = (float)(ng >> 6);
            float y0 = yib[ng], y1 = yib[HW + ng], y2 = yib[2*HW + ng];
            float cm = fmaxf(colm[nl], colm[128 + nl]);
            float cs = 0.f;
            #pragma unroll
            for (int j = 0; j < 4; ++j) {
                float av = acc[i][j][r];
                float e = __expf((av - bm[j]) * INV_T);
                er[r][j] = e;
                a6[j][0] += e;      a6[j][1] += e*xc; a6[j][2] += e*yc;
                a6[j][3] += e*y0;   a6[j][4] += e*y1; a6[j][5] += e*y2;
                float ev = __expf((av - cm) * INV_T);
                ec[r][j] = ev;
                cs += ev;
            }
            #pragma unroll
            for (int d = 1; d < 16; d <<= 1) cs += __shfl_xor(cs, d);
            if ((lane & 15) == 0) colsm[wn*128 + nl] = cs;
        }
        #pragma unroll
        for (int j = 0; j < 4; ++j) {
            f16x4 pr, pc;
            #pragma unroll
            for (int r = 0; r < 4; ++r) { pr[r] = (_Float16)er[r][j]; pc[r] = (_Float16)ec[r][j]; }
            size_t base = (size_t)mg[j]*HW + n0 + nl0 + i*16;
            *(f16x4*)(Pbr + base) = pr;
            *(f16x4*)(Pbc + base) = pc;
        }
    }
    #pragma unroll
    for (int j = 0; j < 4; ++j)
        #pragma unroll
        for (int q = 0; q < 6; ++q) {
            float v = a6[j][q];
            v += __shfl_xor(v, 16);
            v += __shfl_xor(v, 32);
            if ((lane >> 4) == 0) sums6[(wm*128 + wn*64 + j*16 + lane)*6 + q] = v;
        }
    __syncthreads();

    // phase C: global partial writes
    if (tid < 128) {
        int ml = tid;
        float m2 = fmaxf(rowm[ml], rowm[128 + ml]);
        rowp[((size_t)blockIdx.x*7 + 0)*HW + m0 + ml] = m2;
        rmb[(size_t)blockIdx.x*HW + m0 + ml] = m2;
        #pragma unroll
        for (int q = 0; q < 6; ++q)
            rowp[((size_t)blockIdx.x*7 + 1 + q)*HW + m0 + ml] =
                sums6[ml*6 + q] + sums6[(128 + ml)*6 + q];
    } else {
        int nl = tid - 128;
        float c2 = fmaxf(colm[nl], colm[128 + nl]);
        colp[((size_t)blockIdx.y*2 + 0)*HW + n0 + nl] = c2;
        cmb[(size_t)blockIdx.y*HW + n0 + nl] = c2;
        colp[((size_t)blockIdx.y*2 + 1)*HW + n0 + nl] = colsm[nl] + colsm[128 + nl];
    }
}

// merged combine: y==0 -> row stats; y==1 -> col stats
__global__ void rowcol_combine_kernel(const float* __restrict__ rowp,
        const float* __restrict__ colp,
        float* __restrict__ rmax, float* __restrict__ rsuminv,
        float* __restrict__ coords, float* __restrict__ attn,
        float* __restrict__ cmax, float* __restrict__ csuminv, int b) {
    int idx = blockIdx.x * 256 + threadIdx.x;
    if (blockIdx.y == 0) {
        int m = idx;
        float gm = -3.0e38f;
        for (int t = 0; t < 32; ++t) gm = fmaxf(gm, rowp[((size_t)t*7)*HW + m]);
        float S=0, CX=0, CY=0, A0=0, A1=0, A2=0;
        for (int t = 0; t < 32; ++t) {
            const float* p = rowp + (size_t)t*7*HW + m;
            float wgt = __expf((p[0] - gm) * INV_T);
            S  += p[1*HW] * wgt; CX += p[2*HW] * wgt; CY += p[3*HW] * wgt;
            A0 += p[4*HW] * wgt; A1 += p[5*HW] * wgt; A2 += p[6*HW] * wgt;
        }
        float inv = 1.0f / S;
        rmax[m] = gm; rsuminv[m] = inv;
        coords[((size_t)b*2 + 0)*HW + m] = CX * inv;
        coords[((size_t)b*2 + 1)*HW + m] = CY * inv;
        attn[((size_t)b*HW + m)*3 + 0] = A0 * inv;
        attn[((size_t)b*HW + m)*3 + 1] = A1 * inv;
        attn[((size_t)b*HW + m)*3 + 2] = A2 * inv;
    } else {
        int n = idx;
        float gm = -3.0e38f;
        for (int t = 0; t < 32; ++t) gm = fmaxf(gm, colp[((size_t)t*2)*HW + n]);
        float S = 0.f;
        for (int t = 0; t < 32; ++t) {
            const float* p = colp + (size_t)t*2*HW + n;
            S += p[1*HW] * __expf((p[0] - gm) * INV_T);
        }
        cmax[n] = gm;
        csuminv[n] = 1.0f / S;
    }
}

// y partials: A = Pb_row(f16) * corr (per 128-K tile), B = yf16. split-K=4, 64m x 256c.
__global__ __launch_bounds__(512) void gemm_y_kernel(const _Float16* __restrict__ Pbr,
        const float* __restrict__ rmax, const float* __restrict__ rmb,
        const _Float16* __restrict__ yf16, _Float16* __restrict__ yph, int b) {
    __shared__ __align__(16) char ldsA[4096];    // P tile [64 m][32 k] f16
    __shared__ __align__(16) char ldsB[16384];   // Y tile [256 c][32 k] f16
    int tid  = threadIdx.x;
    int lane = tid & 63;
    int w = tid >> 6, wm = w >> 2, wn = w & 3;
    int m0 = blockIdx.x * 64;
    int ks = blockIdx.y;
    const _Float16* Yb = yf16 + (size_t)b * NCH * HW;

    int ar = (tid & 255) >> 2, akc = tid & 3;
    int aoff = ar*64 + ((akc ^ ((ar >> 1) & 3)) << 4);
    float gm = rmax[m0 + ar];
    const _Float16* prow = Pbr + (size_t)(m0 + ar)*HW + akc*8;
    const float* rmbm = rmb + (m0 + ar);

    int o0 = tid*16, o1 = o0 + 8192;
    int br0 = o0 >> 6, bs0 = (o0 >> 4) & 3, bg0 = bs0 ^ ((br0 >> 1) & 3);
    int br1 = o1 >> 6, bs1 = (o1 >> 4) & 3, bg1 = bs1 ^ ((br1 >> 1) & 3);
    size_t gb0 = (size_t)br0*HW + bg0*8;
    size_t gb1 = (size_t)br1*HW + bg1*8;

    int fra = wm*32 + (lane & 15);
    int frb = wn*64 + (lane & 15);
    int kslot = lane >> 4;

    f32x4 acc[2][4];
    #pragma unroll
    for (int i = 0; i < 2; ++i)
        #pragma unroll
        for (int j = 0; j < 4; ++j) acc[i][j] = (f32x4){0.f, 0.f, 0.f, 0.f};

    _Float16 corrh = (_Float16)0.f;
    for (int k0 = ks*1024; k0 < ks*1024 + 1024; k0 += 32) {
        gload16(Yb + gb0 + k0, &ldsB[o0]);
        gload16(Yb + gb1 + k0, &ldsB[o1]);
        if (tid < 256) {
            if ((k0 & 127) == 0)
                corrh = (_Float16)__expf((rmbm[(size_t)(k0 >> 7)*HW] - gm) * INV_T);
            f16x8 pb = *(const f16x8*)(prow + k0);
            f16x8 pk;
            #pragma unroll
            for (int q = 0; q < 8; ++q) pk[q] = pb[q] * corrh;
            *(f16x8*)&ldsA[aoff] = pk;
        }
        __syncthreads();

        f16x8 af[2], bf[4];
        #pragma unroll
        for (int i = 0; i < 2; ++i) {
            int rowa = fra + i*16;
            af[i] = *(const f16x8*)&ldsA[rowa*64 + ((kslot ^ ((rowa >> 1) & 3)) << 4)];
        }
        #pragma unroll
        for (int j = 0; j < 4; ++j) {
            int rowb = frb + j*16;
            bf[j] = *(const f16x8*)&ldsB[rowb*64 + ((kslot ^ ((rowb >> 1) & 3)) << 4)];
        }
        #pragma unroll
        for (int i = 0; i < 2; ++i)
            #pragma unroll
            for (int j = 0; j < 4; ++j)
                acc[i][j] = __builtin_amdgcn_mfma_f32_16x16x32_f16(af[i], bf[j], acc[i][j], 0, 0, 0);
        __syncthreads();
    }

    #pragma unroll
    for (int i = 0; i < 2; ++i) {
        int m = m0 + wm*32 + i*16 + (lane >> 4) * 4;
        #pragma unroll
        for (int j = 0; j < 4; ++j) {
            int c = wn*64 + j*16 + (lane & 15);
            f16x4 v;
            #pragma unroll
            for (int r = 0; r < 4; ++r) v[r] = (_Float16)acc[i][j][r];
            *(f16x4*)(yph + ((size_t)ks*NCH + c)*HW + m) = v;
        }
    }
}

__global__ void ycombine_kernel(const _Float16* __restrict__ yph, const float* __restrict__ rsuminv,
                                float* __restrict__ out, int b) {
    size_t idx = (size_t)blockIdx.x * 256 + threadIdx.x;
    int m = (int)(idx & (HW - 1));
    float s = 0.f;
    #pragma unroll
    for (int k = 0; k < 4; ++k) s += (float)yph[(size_t)k*NCH*HW + idx];
    out[OUT_Y + (size_t)b*NCH*HW + idx] = s * rsuminv[m];
}

// cyc partial: reads Pb_col f16 + one prologue exp per thread
__global__ __launch_bounds__(256) void cyc_partial_kernel(const _Float16* __restrict__ Pbc,
        const float* __restrict__ cmax, const float* __restrict__ cmb,
        const float* __restrict__ attn, float* __restrict__ part, int b) {
    __shared__ float at[128*3];
    int i  = blockIdx.x * 256 + threadIdx.x;
    int j0 = blockIdx.y * 128;
    int tm = blockIdx.y;
    for (int k = threadIdx.x; k < 384; k += 256)
        at[k] = attn[((size_t)b*HW + j0)*3 + k];
    __syncthreads();
    // corrc = exp((cmb - cmax)/T) <= 1 (cmb is block col max, cmax global col max)
    float corrc = __expf((cmb[(size_t)tm*HW + i] - cmax[i]) * INV_T);
    float a0=0, a1=0, a2=0;
    for (int jj = 0; jj < 128; ++jj) {
        float e = (float)Pbc[(size_t)(j0+jj)*HW + i] * corrc;
        a0 = fmaf(e, at[jj*3+0], a0);
        a1 = fmaf(e, at[jj*3+1], a1);
        a2 = fmaf(e, at[jj*3+2], a2);
    }
    part[((size_t)blockIdx.y*3 + 0)*HW + i] = a0;
    part[((size_t)blockIdx.y*3 + 1)*HW + i] = a1;
    part[((size_t)blockIdx.y*3 + 2)*HW + i] = a2;
}

__global__ void cyc_combine_kernel(const float* __restrict__ part, const float* __restrict__ csuminv,
                                   float* __restrict__ cyc, int b) {
    int i = blockIdx.x * 256 + threadIdx.x;
    int c = blockIdx.y;
    float s = 0.f;
    for (int k = 0; k < 32; ++k) s += part[((size_t)k*3 + c)*HW + i];
    cyc[((size_t)b*3 + c)*HW + i] = s * csuminv[i];
}

__global__ void flow_kernel(const float* __restrict__ coords, float* __restrict__ out) {
    size_t idx = (size_t)blockIdx.x * 256 + threadIdx.x;
    int x4 = (int)(idx & 255);
    int y4 = (int)((idx >> 8) & 255);
    int ch = (int)((idx >> 16) & 1);
    int b  = (int)(idx >> 17);
    int w = x4 >> 2, h = y4 >> 2;
    int m = h*64 + w;
    float c1 = coords[((size_t)b*2 + ch)*HW + m];
    float c0 = (ch == 0) ? (float)w : (float)h;
    out[OUT_FLOW + idx] = c1 - c0;
}

__global__ void imgout_kernel(const float* __restrict__ attn, const float* __restrict__ cyc,
                              float* __restrict__ out) {
    size_t idx = (size_t)blockIdx.x * 256 + threadIdx.x;
    int x4 = (int)(idx & 255);
    int y4 = (int)((idx >> 8) & 255);
    int rest = (int)(idx >> 16);
    int ch = rest % 3, b = rest / 3;
    int m = (y4 >> 2)*64 + (x4 >> 2);
    out[OUT_IMG  + idx] = attn[((size_t)b*HW + m)*3 + ch];
    out[OUT_CYCO + idx] = cyc[((size_t)b*3 + ch)*HW + m];
}

__global__ void loss_partial_kernel(const float* __restrict__ xf, const float* __restrict__ yf,
                                    const float* __restrict__ means, const float* __restrict__ rnorms,
                                    float* __restrict__ part) {
    __shared__ float red[256];
    size_t base = (size_t)blockIdx.x * 4096;
    float s = 0.f;
    for (int k = 0; k < 16; ++k) {
        size_t id = base + (size_t)k*256 + threadIdx.x;
        int m  = (int)(id & (HW - 1));
        int bc = (int)(id >> 12);
        int b  = bc >> 8;
        float th = (xf[id] - means[bc])          * rnorms[(size_t)b*HW + m];
        float ph = (yf[id] - means[NB*NCH + bc]) * rnorms[(size_t)(NB + b)*HW + m];
        s += fabsf(th - ph);
    }
    red[threadIdx.x] = s; __syncthreads();
    for (int st = 128; st > 0; st >>= 1) {
        if (threadIdx.x < st) red[threadIdx.x] += red[threadIdx.x + st];
        __syncthreads();
    }
    if (threadIdx.x == 0) part[blockIdx.x] = red[0];
}

__global__ void loss_final_kernel(const float* __restrict__ part, float* __restrict__ out) {
    __shared__ float red[256];
    float s = 0.f;
    for (int k = threadIdx.x; k < 1024; k += 256) s += part[k];
    red[threadIdx.x] = s; __syncthreads();
    for (int st = 128; st > 0; st >>= 1) {
        if (threadIdx.x < st) red[threadIdx.x] += red[threadIdx.x + st];
        __syncthreads();
    }
    if (threadIdx.x == 0) out[OUT_LOSS] = red[0] * (1.0f / 4194304.0f);
}

extern "C" void kernel_launch(void* const* d_in, const int* in_sizes, int n_in,
                              void* d_out, int out_size, void* d_ws, size_t ws_size,
                              hipStream_t stream) {
    (void)in_sizes; (void)n_in; (void)out_size; (void)ws_size;
    const float* xf   = (const float*)d_in[0];
    const float* yf   = (const float*)d_in[1];
    const float* yimg = (const float*)d_in[2];
    float* out = (float*)d_out;
    float* ws  = (float*)d_ws;

    _Float16* yf16 = (_Float16*)(ws + OFF_YT);
    float* yi      = ws + OFF_YI;
    float* means   = ws + OFF_MEAN;
    float* rnorms  = ws + OFF_RNORM;
    float* nsqp    = ws + OFF_NSQP;
    _Float16* Pbr  = (_Float16*)(ws + OFF_PB);
    _Float16* Pbc  = Pbr + (size_t)HW*HW;
    _Float16* yph  = (_Float16*)(ws + OFF_YP);
    float* rowp    = ws + OFF_ROWP;
    float* colp    = ws + OFF_COLP;
    float* rmax    = ws + OFF_RMAX;
    float* rsuminv = ws + OFF_RSUM;
    float* cmax    = ws + OFF_CMAX;
    float* csuminv = ws + OFF_CSUM;
    float* rmb     = ws + OFF_RMB;
    float* cmb     = ws + OFF_CMB;
    float* coords  = ws + OFF_COORD;
    float* attn    = ws + OFF_ATTN;
    float* cyc     = ws + OFF_CYC;
    float* cycp    = ws + OFF_CYCP;
    float* lossp   = ws + OFF_LOSSP;
    _Float16* th = (_Float16*)(ws + OFF_F16);
    _Float16* tl = th + (size_t)HW*NCH;
    _Float16* ph = tl + (size_t)HW*NCH;
    _Float16* pl = ph + (size_t)HW*NCH;

    mean_kernel        <<<dim3(NB*NCH, 2),   256, 0, stream>>>(xf, yf, means);
    nsq_partial_kernel <<<dim3(16, 8, 8),    256, 0, stream>>>(xf, yf, means, nsqp);
    nsq_combine_kernel <<<dim3(16, 8),       256, 0, stream>>>(nsqp, rnorms);
    ycast_kernel       <<<2048,              256, 0, stream>>>(yf, yf16);
    avgpool_kernel     <<<NB*3*HW/256,       256, 0, stream>>>(yimg, yi);

    for (int b = 0; b < NB; ++b) {
        prep_kernel          <<<dim3(8, 128, 2), 256, 0, stream>>>(xf, yf, means, th, tl, ph, pl, b);
        gemm_f_kernel        <<<dim3(32, 32),    256, 0, stream>>>(th, tl, ph, pl, rnorms, yi,
                                                                   Pbr, Pbc, rowp, colp, rmb, cmb, b);
        rowcol_combine_kernel<<<dim3(16, 2),     256, 0, stream>>>(rowp, colp, rmax, rsuminv,
                                                                   coords, attn, cmax, csuminv, b);
        cyc_partial_kernel   <<<dim3(16, 32),    256, 0, stream>>>(Pbc, cmax, cmb, attn, cycp, b);
        cyc_combine_kernel   <<<dim3(16, 3),     256, 0, stream>>>(cycp, csuminv, cyc, b);
        gemm_y_kernel        <<<dim3(64, 4),     512, 0, stream>>>(Pbr, rmax, rmb, yf16, yph, b);
        ycombine_kernel      <<<NCH*HW/256,      256, 0, stream>>>(yph, rsuminv, out, b);
    }

    flow_kernel        <<<NB*2*65536/256, 256, 0, stream>>>(coords, out);
    imgout_kernel      <<<NB*3*65536/256, 256, 0, stream>>>(attn, cyc, out);
    loss_partial_kernel<<<1024,           256, 0, stream>>>(xf, yf, means, rnorms, lossp);
    loss_final_kernel  <<<1,              256, 0, stream>>>(lossp, out);
}

// Round 11
// 527.867 us; speedup vs baseline: 1.1208x; 1.1208x over previous
//
#include <hip/hip_runtime.h>
#include <math.h>

#define HW   4096
#define NCH  256
#define NB   4

constexpr float TEMP  = (float)(0.0001 * 5.0);
constexpr float INV_T = 1.0f / TEMP;
constexpr float EPSN  = 2.220446049250313e-16f;

typedef __attribute__((ext_vector_type(8))) _Float16 f16x8;
typedef __attribute__((ext_vector_type(4))) _Float16 f16x4;
typedef __attribute__((ext_vector_type(4))) float    f32x4;

// ---------------- workspace layout (in floats) ----------------
constexpr size_t OFF_YT    = 0;                                 // yf16: NB*HW*NCH f16
constexpr size_t OFF_YI    = OFF_YT    + (size_t)NB*HW*NCH;     // NB*3*HW
constexpr size_t OFF_MEAN  = OFF_YI    + (size_t)NB*3*HW;       // 2*NB*NCH
constexpr size_t OFF_RNORM = OFF_MEAN  + (size_t)2*NB*NCH;      // 2*NB*HW
constexpr size_t OFF_NSQP  = OFF_RNORM + (size_t)2*NB*HW;       // 2*NB*8*HW
constexpr size_t OFF_F     = OFF_NSQP  + (size_t)2*NB*8*HW;     // HW*HW (f32 f)
constexpr size_t OFF_YP    = OFF_F     + (size_t)HW*HW;         // region reused
// rowp/colp ALIAS the yp region: consumed by combine before gemm_y writes yph
constexpr size_t OFF_ROWP  = OFF_YP;                            // [32 ntile][7][HW]
constexpr size_t OFF_COLP  = OFF_YP + (size_t)32*7*HW;          // [32 mtile][2][HW]
constexpr size_t OFF_RMAX  = OFF_YP    + (size_t)8*NCH*HW;
constexpr size_t OFF_RSUM  = OFF_RMAX  + HW;
constexpr size_t OFF_CMAX  = OFF_RSUM  + HW;
constexpr size_t OFF_CSUM  = OFF_CMAX  + HW;
constexpr size_t OFF_COORD = OFF_CSUM  + HW;                // NB*2*HW
constexpr size_t OFF_ATTN  = OFF_COORD + (size_t)NB*2*HW;   // NB*HW*3
constexpr size_t OFF_CYC   = OFF_ATTN  + (size_t)NB*HW*3;   // NB*3*HW
constexpr size_t OFF_CYCP  = OFF_CYC   + (size_t)NB*3*HW;   // 32*3*HW
constexpr size_t OFF_LOSSP = OFF_CYCP  + (size_t)32*3*HW;   // 1024
constexpr size_t OFF_F16   = OFF_LOSSP + 1024;              // 4 * 524288 floats

// ---------------- output layout (floats) ----------------
constexpr size_t OUT_Y    = 0;
constexpr size_t OUT_FLOW = (size_t)NB*NCH*HW;
constexpr size_t OUT_IMG  = OUT_FLOW + (size_t)NB*2*256*256;
constexpr size_t OUT_CYCO = OUT_IMG  + (size_t)NB*3*256*256;
constexpr size_t OUT_LOSS = OUT_CYCO + (size_t)NB*3*256*256;

__device__ __forceinline__ void gload16(const void* g, void* l) {
    __builtin_amdgcn_global_load_lds(
        (const __attribute__((address_space(1))) unsigned int*)g,
        (__attribute__((address_space(3))) unsigned int*)l, 16, 0, 0);
}

__global__ void mean_kernel(const float* __restrict__ xf, const float* __restrict__ yf,
                            float* __restrict__ means) {
    const float* src = (blockIdx.y == 0 ? xf : yf) + (size_t)blockIdx.x * HW;
    float s = 0.f;
    for (int i = threadIdx.x; i < HW; i += 256) s += src[i];
    __shared__ float red[256];
    red[threadIdx.x] = s; __syncthreads();
    for (int st = 128; st > 0; st >>= 1) {
        if (threadIdx.x < st) red[threadIdx.x] += red[threadIdx.x + st];
        __syncthreads();
    }
    if (threadIdx.x == 0) means[blockIdx.y * (NB*NCH) + blockIdx.x] = red[0] * (1.0f / HW);
}

// per-batch combine of nsq partials written by prep_kernel
__global__ void nsq_combine_kernel(const float* __restrict__ part, float* __restrict__ rnorms,
                                   int b) {
    int t = blockIdx.y;
    int m = blockIdx.x * 256 + threadIdx.x;
    const float* p = part + ((size_t)t*NB + b) * 8 * HW + m;
    float s = 0.f;
    for (int k = 0; k < 8; ++k) s += p[(size_t)k * HW];
    rnorms[((size_t)t*NB + b) * HW + m] = 1.0f / (sqrtf(s) + EPSN);
}

__global__ void ycast_kernel(const float* __restrict__ yf, _Float16* __restrict__ yf16) {
    size_t i = ((size_t)blockIdx.x * 256 + threadIdx.x) * 8;
    const float4* s = (const float4*)(yf + i);
    float4 v0 = s[0], v1 = s[1];
    f16x8 o;
    o[0]=(_Float16)v0.x; o[1]=(_Float16)v0.y; o[2]=(_Float16)v0.z; o[3]=(_Float16)v0.w;
    o[4]=(_Float16)v1.x; o[5]=(_Float16)v1.y; o[6]=(_Float16)v1.z; o[7]=(_Float16)v1.w;
    *(f16x8*)(yf16 + i) = o;
}

// centered hi/lo f16 split in transposed [m][c] layout + nsq partials (fused)
__global__ void prep_kernel(const float* __restrict__ xf, const float* __restrict__ yf,
                            const float* __restrict__ means,
                            _Float16* __restrict__ th, _Float16* __restrict__ tl,
                            _Float16* __restrict__ ph, _Float16* __restrict__ pl,
                            float* __restrict__ nsqp, int b) {
    __shared__ float tile[32][33];
    __shared__ float sqr[8][33];
    int t = blockIdx.z;
    int c0 = blockIdx.x * 32, m0 = blockIdx.y * 32;
    const float* src = (t == 0 ? xf : yf) + (size_t)b * NCH * HW;
    const float* mn  = means + t * (NB*NCH) + b * NCH;
    int tx = threadIdx.x & 31, ty = threadIdx.x >> 5;
    float sq = 0.f;
    for (int i = ty; i < 32; i += 8) {
        float v = src[(size_t)(c0 + i) * HW + m0 + tx] - mn[c0 + i];
        tile[i][tx] = v;
        sq += v * v;
    }
    sqr[ty][tx] = sq;
    __syncthreads();
    _Float16* H = (t == 0 ? th : ph);
    _Float16* L = (t == 0 ? tl : pl);
    for (int i = ty; i < 32; i += 8) {
        float v = tile[tx][i];
        _Float16 h = (_Float16)v;
        _Float16 l = (_Float16)(v - (float)h);
        H[(size_t)(m0 + i)*NCH + c0 + tx] = h;
        L[(size_t)(m0 + i)*NCH + c0 + tx] = l;
    }
    if (ty == 0) {
        float s = 0.f;
        #pragma unroll
        for (int k = 0; k < 8; ++k) s += sqr[k][tx];
        nsqp[(((size_t)t*NB + b) * 8 + blockIdx.x) * HW + m0 + tx] = s;
    }
}

__global__ void avgpool_kernel(const float* __restrict__ yimg, float* __restrict__ yi) {
    size_t idx = (size_t)blockIdx.x * 256 + threadIdx.x;
    int m  = (int)(idx & (HW - 1));
    int bc = (int)(idx >> 12);
    int h = m >> 6, w = m & 63;
    const float* p = yimg + (size_t)bc * 65536 + (size_t)(h*4) * 256 + w*4;
    float s = 0.f;
    #pragma unroll
    for (int dy = 0; dy < 4; ++dy) {
        #pragma unroll
        for (int dx = 0; dx < 4; ++dx) s += p[dy*256 + dx];
    }
    yi[idx] = s * (1.0f/16.0f);
}

// f^T accumulator GEMM (R9-proven): 128x128 tile, 4 waves, BK=32, 2-phase dbuf LDS.
__global__ __launch_bounds__(256) void gemm_f_kernel(
        const _Float16* __restrict__ th, const _Float16* __restrict__ tl,
        const _Float16* __restrict__ ph, const _Float16* __restrict__ pl,
        const float* __restrict__ rnorms, const float* __restrict__ yi,
        float* __restrict__ f, float* __restrict__ rowp, float* __restrict__ colp,
        int b) {
    __shared__ char lds[2][4][8192];
    int tid  = threadIdx.x;
    int lane = tid & 63;
    int w = tid >> 6, wm = w >> 1, wn = w & 1;   // wm: n-block, wn: m-block
    int m0 = blockIdx.y * 128, n0 = blockIdx.x * 128;

    int o0 = tid * 16, o1 = o0 + 4096;
    int r0 = o0 >> 6, s0 = (o0 >> 4) & 3, g0 = s0 ^ ((r0 >> 1) & 3);
    int r1 = o1 >> 6, s1 = (o1 >> 4) & 3, g1 = s1 ^ ((r1 >> 1) & 3);
    size_t ga0 = (size_t)(n0 + r0)*NCH + g0*8;
    size_t ga1 = (size_t)(n0 + r1)*NCH + g1*8;
    size_t gb0 = (size_t)(m0 + r0)*NCH + g0*8;
    size_t gb1 = (size_t)(m0 + r1)*NCH + g1*8;

    int fra = wm*64 + (lane & 15);
    int frb = wn*64 + (lane & 15);
    int ks  = lane >> 4;

    auto STAGE = [&](int buf, int k0) {
        gload16(ph + ga0 + k0, &lds[buf][0][o0]);
        gload16(ph + ga1 + k0, &lds[buf][0][o1]);
        gload16(pl + ga0 + k0, &lds[buf][1][o0]);
        gload16(pl + ga1 + k0, &lds[buf][1][o1]);
        gload16(th + gb0 + k0, &lds[buf][2][o0]);
        gload16(th + gb1 + k0, &lds[buf][2][o1]);
        gload16(tl + gb0 + k0, &lds[buf][3][o0]);
        gload16(tl + gb1 + k0, &lds[buf][3][o1]);
    };

    f32x4 acc[4][4];
    #pragma unroll
    for (int i = 0; i < 4; ++i)
        #pragma unroll
        for (int j = 0; j < 4; ++j) acc[i][j] = (f32x4){0.f, 0.f, 0.f, 0.f};

    STAGE(0, 0);
    __syncthreads();
    int cur = 0;
    for (int kt = 0; kt < 8; ++kt) {
        if (kt < 7) STAGE(cur ^ 1, (kt + 1) * 32);

        f16x8 ah[4], al[4], bh[4], bl[4];
        #pragma unroll
        for (int i = 0; i < 4; ++i) {
            int rowa = fra + i*16;
            int offa = rowa*64 + ((ks ^ ((rowa >> 1) & 3)) << 4);
            ah[i] = *(const f16x8*)&lds[cur][0][offa];
            al[i] = *(const f16x8*)&lds[cur][1][offa];
            int rowb = frb + i*16;
            int offb = rowb*64 + ((ks ^ ((rowb >> 1) & 3)) << 4);
            bh[i] = *(const f16x8*)&lds[cur][2][offb];
            bl[i] = *(const f16x8*)&lds[cur][3][offb];
        }
        #pragma unroll
        for (int i = 0; i < 4; ++i)
            #pragma unroll
            for (int j = 0; j < 4; ++j) {
                acc[i][j] = __builtin_amdgcn_mfma_f32_16x16x32_f16(ah[i], bh[j], acc[i][j], 0, 0, 0);
                acc[i][j] = __builtin_amdgcn_mfma_f32_16x16x32_f16(ah[i], bl[j], acc[i][j], 0, 0, 0);
                acc[i][j] = __builtin_amdgcn_mfma_f32_16x16x32_f16(al[i], bh[j], acc[i][j], 0, 0, 0);
            }
        __syncthreads();
        cur ^= 1;
    }

    // ---- scale in place: f[m][n] = accT * rnx[m] * rny[n] ----
    const float* rnx = rnorms + (size_t)b * HW;
    const float* rny = rnorms + (size_t)(NB + b) * HW;
    int mg[4];  float rxv[4];
    #pragma unroll
    for (int j = 0; j < 4; ++j) {
        mg[j] = m0 + wn*64 + j*16 + (lane & 15);
        rxv[j] = rnx[mg[j]];
    }
    int nl0 = wm*64 + (lane >> 4)*4;
    #pragma unroll
    for (int i = 0; i < 4; ++i)
        #pragma unroll
        for (int r = 0; r < 4; ++r) {
            float ry = rny[n0 + nl0 + i*16 + r];
            #pragma unroll
            for (int j = 0; j < 4; ++j) acc[i][j][r] *= rxv[j] * ry;
        }

    // ---- write f: one float4 per (i,j) ----
    #pragma unroll
    for (int j = 0; j < 4; ++j)
        #pragma unroll
        for (int i = 0; i < 4; ++i)
            *(f32x4*)&f[(size_t)mg[j]*HW + n0 + nl0 + i*16] = acc[i][j];

    // ---- stats (deterministic; LDS reuse after final loop barrier) ----
    float* S     = (float*)&lds[0][0][0];
    float* rowm  = S;          // [2 wm][128 m]
    float* sums6 = S + 256;    // [2 wm][128 m][6]
    float* colm  = S + 1792;   // [2 wn][128 n]
    float* colsm = S + 2048;   // [2 wn][128 n]

    // phase A: per-wave maxes
    #pragma unroll
    for (int j = 0; j < 4; ++j) {
        float v = acc[0][j][0];
        #pragma unroll
        for (int i = 0; i < 4; ++i)
            #pragma unroll
            for (int r = 0; r < 4; ++r) v = fmaxf(v, acc[i][j][r]);
        v = fmaxf(v, __shfl_xor(v, 16));
        v = fmaxf(v, __shfl_xor(v, 32));
        if ((lane >> 4) == 0) rowm[wm*128 + wn*64 + j*16 + lane] = v;
    }
    #pragma unroll
    for (int i = 0; i < 4; ++i)
        #pragma unroll
        for (int r = 0; r < 4; ++r) {
            float v = fmaxf(fmaxf(acc[i][0][r], acc[i][1][r]),
                            fmaxf(acc[i][2][r], acc[i][3][r]));
            #pragma unroll
            for (int d = 1; d < 16; d <<= 1) v = fmaxf(v, __shfl_xor(v, d));
            if ((lane & 15) == 0) colm[wn*128 + wm*64 + i*16 + (lane >> 4)*4 + r] = v;
        }
    __syncthreads();

    // phase B: exp sums vs block maxes
    float bm[4];
    #pragma unroll
    for (int j = 0; j < 4; ++j) {
        int ml = wn*64 + j*16 + (lane & 15);
        bm[j] = fmaxf(rowm[ml], rowm[128 + ml]);
    }
    float a6[4][6];
    #pragma unroll
    for (int j = 0; j < 4; ++j)
        #pragma unroll
        for (int q = 0; q < 6; ++q) a6[j][q] = 0.f;
    const float* yib = yi + (size_t)b * 3 * HW;
    #pragma unroll
    for (int i = 0; i < 4; ++i)
        #pragma unroll
        for (int r = 0; r < 4; ++r) {
            int ng = n0 + nl0 + i*16 + r;
            float xc = (float)(ng & 63), yc = (float)(ng >> 6);
            float y0 = yib[ng], y1 = yib[HW + ng], y2 = yib[2*HW + ng];
            #pragma unroll
            for (int j = 0; j < 4; ++j) {
                float e = __expf((acc[i][j][r] - bm[j]) * INV_T);
                a6[j][0] += e;      a6[j][1] += e*xc; a6[j][2] += e*yc;
                a6[j][3] += e*y0;   a6[j][4] += e*y1; a6[j][5] += e*y2;
            }
        }
    #pragma unroll
    for (int j = 0; j < 4; ++j)
        #pragma unroll
        for (int q = 0; q < 6; ++q) {
            float v = a6[j][q];
            v += __shfl_xor(v, 16);
            v += __shfl_xor(v, 32);
            if ((lane >> 4) == 0) sums6[(wm*128 + wn*64 + j*16 + lane)*6 + q] = v;
        }
    #pragma unroll
    for (int i = 0; i < 4; ++i)
        #pragma unroll
        for (int r = 0; r < 4; ++r) {
            int nl = wm*64 + i*16 + (lane >> 4)*4 + r;
            float cm = fmaxf(colm[nl], colm[128 + nl]);
            float cs = 0.f;
            #pragma unroll
            for (int j = 0; j < 4; ++j) cs += __expf((acc[i][j][r] - cm) * INV_T);
            #pragma unroll
            for (int d = 1; d < 16; d <<= 1) cs += __shfl_xor(cs, d);
            if ((lane & 15) == 0) colsm[wn*128 + nl] = cs;
        }
    __syncthreads();

    // phase C: global partial writes
    if (tid < 128) {
        int ml = tid;
        float m2 = fmaxf(rowm[ml], rowm[128 + ml]);
        rowp[((size_t)blockIdx.x*7 + 0)*HW + m0 + ml] = m2;
        #pragma unroll
        for (int q = 0; q < 6; ++q)
            rowp[((size_t)blockIdx.x*7 + 1 + q)*HW + m0 + ml] =
                sums6[ml*6 + q] + sums6[(128 + ml)*6 + q];
    } else {
        int nl = tid - 128;
        float c2 = fmaxf(colm[nl], colm[128 + nl]);
        colp[((size_t)blockIdx.y*2 + 0)*HW + n0 + nl] = c2;
        colp[((size_t)blockIdx.y*2 + 1)*HW + n0 + nl] = colsm[nl] + colsm[128 + nl];
    }
}

// merged combine: y==0 -> row stats; y==1 -> col stats
__global__ void rowcol_combine_kernel(const float* __restrict__ rowp,
        const float* __restrict__ colp,
        float* __restrict__ rmax, float* __restrict__ rsuminv,
        float* __restrict__ coords, float* __restrict__ attn,
        float* __restrict__ cmax, float* __restrict__ csuminv, int b) {
    int idx = blockIdx.x * 256 + threadIdx.x;
    if (blockIdx.y == 0) {
        int m = idx;
        float gm = -3.0e38f;
        for (int t = 0; t < 32; ++t) gm = fmaxf(gm, rowp[((size_t)t*7)*HW + m]);
        float S=0, CX=0, CY=0, A0=0, A1=0, A2=0;
        for (int t = 0; t < 32; ++t) {
            const float* p = rowp + (size_t)t*7*HW + m;
            float wgt = __expf((p[0] - gm) * INV_T);
            S  += p[1*HW] * wgt; CX += p[2*HW] * wgt; CY += p[3*HW] * wgt;
            A0 += p[4*HW] * wgt; A1 += p[5*HW] * wgt; A2 += p[6*HW] * wgt;
        }
        float inv = 1.0f / S;
        rmax[m] = gm; rsuminv[m] = inv;
        coords[((size_t)b*2 + 0)*HW + m] = CX * inv;
        coords[((size_t)b*2 + 1)*HW + m] = CY * inv;
        attn[((size_t)b*HW + m)*3 + 0] = A0 * inv;
        attn[((size_t)b*HW + m)*3 + 1] = A1 * inv;
        attn[((size_t)b*HW + m)*3 + 2] = A2 * inv;
    } else {
        int n = idx;
        float gm = -3.0e38f;
        for (int t = 0; t < 32; ++t) gm = fmaxf(gm, colp[((size_t)t*2)*HW + n]);
        float S = 0.f;
        for (int t = 0; t < 32; ++t) {
            const float* p = colp + (size_t)t*2*HW + n;
            S += p[1*HW] * __expf((p[0] - gm) * INV_T);
        }
        cmax[n] = gm;
        csuminv[n] = 1.0f / S;
    }
}

// y partials: MFMA f16, split-K=4, tile 64m x 256c, 8 waves; f16 partial output.
__global__ __launch_bounds__(512) void gemm_y_kernel(const float* __restrict__ f,
        const float* __restrict__ rmax, const _Float16* __restrict__ yf16,
        _Float16* __restrict__ yph, int b) {
    __shared__ __align__(16) char ldsA[4096];    // P tile [64 m][32 k] f16
    __shared__ __align__(16) char ldsB[16384];   // Y tile [256 c][32 k] f16
    int tid  = threadIdx.x;
    int lane = tid & 63;
    int w = tid >> 6, wm = w >> 2, wn = w & 3;
    int m0 = blockIdx.x * 64;
    int ks = blockIdx.y;
    const _Float16* Yb = yf16 + (size_t)b * NCH * HW;

    int ar = (tid & 255) >> 2, akc = tid & 3;
    int aoff = ar*64 + ((akc ^ ((ar >> 1) & 3)) << 4);
    float arm = rmax[m0 + ar];
    const float* frow = f + (size_t)(m0 + ar)*HW + akc*8;

    int o0 = tid*16, o1 = o0 + 8192;
    int br0 = o0 >> 6, bs0 = (o0 >> 4) & 3, bg0 = bs0 ^ ((br0 >> 1) & 3);
    int br1 = o1 >> 6, bs1 = (o1 >> 4) & 3, bg1 = bs1 ^ ((br1 >> 1) & 3);
    size_t gb0 = (size_t)br0*HW + bg0*8;
    size_t gb1 = (size_t)br1*HW + bg1*8;

    int fra = wm*32 + (lane & 15);
    int frb = wn*64 + (lane & 15);
    int kslot = lane >> 4;

    f32x4 acc[2][4];
    #pragma unroll
    for (int i = 0; i < 2; ++i)
        #pragma unroll
        for (int j = 0; j < 4; ++j) acc[i][j] = (f32x4){0.f, 0.f, 0.f, 0.f};

    for (int k0 = ks*1024; k0 < ks*1024 + 1024; k0 += 32) {
        gload16(Yb + gb0 + k0, &ldsB[o0]);
        gload16(Yb + gb1 + k0, &ldsB[o1]);
        if (tid < 256) {
            const float4* fp = (const float4*)(frow + k0);
            float4 v0 = fp[0], v1 = fp[1];
            f16x8 pk;
            pk[0] = (_Float16)__expf((v0.x - arm) * INV_T);
            pk[1] = (_Float16)__expf((v0.y - arm) * INV_T);
            pk[2] = (_Float16)__expf((v0.z - arm) * INV_T);
            pk[3] = (_Float16)__expf((v0.w - arm) * INV_T);
            pk[4] = (_Float16)__expf((v1.x - arm) * INV_T);
            pk[5] = (_Float16)__expf((v1.y - arm) * INV_T);
            pk[6] = (_Float16)__expf((v1.z - arm) * INV_T);
            pk[7] = (_Float16)__expf((v1.w - arm) * INV_T);
            *(f16x8*)&ldsA[aoff] = pk;
        }
        __syncthreads();

        f16x8 af[2], bf[4];
        #pragma unroll
        for (int i = 0; i < 2; ++i) {
            int rowa = fra + i*16;
            af[i] = *(const f16x8*)&ldsA[rowa*64 + ((kslot ^ ((rowa >> 1) & 3)) << 4)];
        }
        #pragma unroll
        for (int j = 0; j < 4; ++j) {
            int rowb = frb + j*16;
            bf[j] = *(const f16x8*)&ldsB[rowb*64 + ((kslot ^ ((rowb >> 1) & 3)) << 4)];
        }
        #pragma unroll
        for (int i = 0; i < 2; ++i)
            #pragma unroll
            for (int j = 0; j < 4; ++j)
                acc[i][j] = __builtin_amdgcn_mfma_f32_16x16x32_f16(af[i], bf[j], acc[i][j], 0, 0, 0);
        __syncthreads();
    }

    #pragma unroll
    for (int i = 0; i < 2; ++i) {
        int m = m0 + wm*32 + i*16 + (lane >> 4) * 4;
        #pragma unroll
        for (int j = 0; j < 4; ++j) {
            int c = wn*64 + j*16 + (lane & 15);
            f16x4 v;
            #pragma unroll
            for (int r = 0; r < 4; ++r) v[r] = (_Float16)acc[i][j][r];
            *(f16x4*)(yph + ((size_t)ks*NCH + c)*HW + m) = v;
        }
    }
}

__global__ void ycombine_kernel(const _Float16* __restrict__ yph, const float* __restrict__ rsuminv,
                                float* __restrict__ out, int b) {
    size_t idx = (size_t)blockIdx.x * 256 + threadIdx.x;
    int m = (int)(idx & (HW - 1));
    float s = 0.f;
    #pragma unroll
    for (int k = 0; k < 4; ++k) s += (float)yph[(size_t)k*NCH*HW + idx];
    out[OUT_Y + (size_t)b*NCH*HW + idx] = s * rsuminv[m];
}

// cyc partial over row-chunks of 128 (512 blocks)
__global__ __launch_bounds__(256) void cyc_partial_kernel(const float* __restrict__ f,
        const float* __restrict__ cmax, const float* __restrict__ attn,
        float* __restrict__ part, int b) {
    __shared__ float at[128*3];
    int i  = blockIdx.x * 256 + threadIdx.x;
    int j0 = blockIdx.y * 128;
    for (int k = threadIdx.x; k < 384; k += 256)
        at[k] = attn[((size_t)b*HW + j0)*3 + k];
    __syncthreads();
    float cm = cmax[i];
    float a0=0, a1=0, a2=0;
    for (int jj = 0; jj < 128; ++jj) {
        float e = __expf((f[(size_t)(j0+jj)*HW + i] - cm) * INV_T);
        a0 = fmaf(e, at[jj*3+0], a0);
        a1 = fmaf(e, at[jj*3+1], a1);
        a2 = fmaf(e, at[jj*3+2], a2);
    }
    part[((size_t)blockIdx.y*3 + 0)*HW + i] = a0;
    part[((size_t)blockIdx.y*3 + 1)*HW + i] = a1;
    part[((size_t)blockIdx.y*3 + 2)*HW + i] = a2;
}

__global__ void cyc_combine_kernel(const float* __restrict__ part, const float* __restrict__ csuminv,
                                   float* __restrict__ cyc, int b) {
    int i = blockIdx.x * 256 + threadIdx.x;
    int c = blockIdx.y;
    float s = 0.f;
    for (int k = 0; k < 32; ++k) s += part[((size_t)k*3 + c)*HW + i];
    cyc[((size_t)b*3 + c)*HW + i] = s * csuminv[i];
}

__global__ void flow_kernel(const float* __restrict__ coords, float* __restrict__ out) {
    size_t idx = (size_t)blockIdx.x * 256 + threadIdx.x;
    int x4 = (int)(idx & 255);
    int y4 = (int)((idx >> 8) & 255);
    int ch = (int)((idx >> 16) & 1);
    int b  = (int)(idx >> 17);
    int w = x4 >> 2, h = y4 >> 2;
    int m = h*64 + w;
    float c1 = coords[((size_t)b*2 + ch)*HW + m];
    float c0 = (ch == 0) ? (float)w : (float)h;
    out[OUT_FLOW + idx] = c1 - c0;
}

__global__ void imgout_kernel(const float* __restrict__ attn, const float* __restrict__ cyc,
                              float* __restrict__ out) {
    size_t idx = (size_t)blockIdx.x * 256 + threadIdx.x;
    int x4 = (int)(idx & 255);
    int y4 = (int)((idx >> 8) & 255);
    int rest = (int)(idx >> 16);
    int ch = rest % 3, b = rest / 3;
    int m = (y4 >> 2)*64 + (x4 >> 2);
    out[OUT_IMG  + idx] = attn[((size_t)b*HW + m)*3 + ch];
    out[OUT_CYCO + idx] = cyc[((size_t)b*3 + ch)*HW + m];
}

__global__ void loss_partial_kernel(const float* __restrict__ xf, const float* __restrict__ yf,
                                    const float* __restrict__ means, const float* __restrict__ rnorms,
                                    float* __restrict__ part) {
    __shared__ float red[256];
    size_t base = (size_t)blockIdx.x * 4096;
    float s = 0.f;
    for (int k = 0; k < 16; ++k) {
        size_t id = base + (size_t)k*256 + threadIdx.x;
        int m  = (int)(id & (HW - 1));
        int bc = (int)(id >> 12);
        int b  = bc >> 8;
        float th = (xf[id] - means[bc])          * rnorms[(size_t)b*HW + m];
        float ph = (yf[id] - means[NB*NCH + bc]) * rnorms[(size_t)(NB + b)*HW + m];
        s += fabsf(th - ph);
    }
    red[threadIdx.x] = s; __syncthreads();
    for (int st = 128; st > 0; st >>= 1) {
        if (threadIdx.x < st) red[threadIdx.x] += red[threadIdx.x + st];
        __syncthreads();
    }
    if (threadIdx.x == 0) part[blockIdx.x] = red[0];
}

__global__ void loss_final_kernel(const float* __restrict__ part, float* __restrict__ out) {
    __shared__ float red[256];
    float s = 0.f;
    for (int k = threadIdx.x; k < 1024; k += 256) s += part[k];
    red[threadIdx.x] = s; __syncthreads();
    for (int st = 128; st > 0; st >>= 1) {
        if (threadIdx.x < st) red[threadIdx.x] += red[threadIdx.x + st];
        __syncthreads();
    }
    if (threadIdx.x == 0) out[OUT_LOSS] = red[0] * (1.0f / 4194304.0f);
}

extern "C" void kernel_launch(void* const* d_in, const int* in_sizes, int n_in,
                              void* d_out, int out_size, void* d_ws, size_t ws_size,
                              hipStream_t stream) {
    (void)in_sizes; (void)n_in; (void)out_size; (void)ws_size;
    const float* xf   = (const float*)d_in[0];
    const float* yf   = (const float*)d_in[1];
    const float* yimg = (const float*)d_in[2];
    float* out = (float*)d_out;
    float* ws  = (float*)d_ws;

    _Float16* yf16 = (_Float16*)(ws + OFF_YT);
    float* yi      = ws + OFF_YI;
    float* means   = ws + OFF_MEAN;
    float* rnorms  = ws + OFF_RNORM;
    float* nsqp    = ws + OFF_NSQP;
    float* fbuf    = ws + OFF_F;
    _Float16* yph  = (_Float16*)(ws + OFF_YP);
    float* rowp    = ws + OFF_ROWP;
    float* colp    = ws + OFF_COLP;
    float* rmax    = ws + OFF_RMAX;
    float* rsuminv = ws + OFF_RSUM;
    float* cmax    = ws + OFF_CMAX;
    float* csuminv = ws + OFF_CSUM;
    float* coords  = ws + OFF_COORD;
    float* attn    = ws + OFF_ATTN;
    float* cyc     = ws + OFF_CYC;
    float* cycp    = ws + OFF_CYCP;
    float* lossp   = ws + OFF_LOSSP;
    _Float16* th = (_Float16*)(ws + OFF_F16);
    _Float16* tl = th + (size_t)HW*NCH;
    _Float16* ph = tl + (size_t)HW*NCH;
    _Float16* pl = ph + (size_t)HW*NCH;

    mean_kernel        <<<dim3(NB*NCH, 2),   256, 0, stream>>>(xf, yf, means);
    ycast_kernel       <<<2048,              256, 0, stream>>>(yf, yf16);
    avgpool_kernel     <<<NB*3*HW/256,       256, 0, stream>>>(yimg, yi);

    for (int b = 0; b < NB; ++b) {
        prep_kernel          <<<dim3(8, 128, 2), 256, 0, stream>>>(xf, yf, means, th, tl, ph, pl,
                                                                   nsqp, b);
        nsq_combine_kernel   <<<dim3(16, 2),     256, 0, stream>>>(nsqp, rnorms, b);
        gemm_f_kernel        <<<dim3(32, 32),    256, 0, stream>>>(th, tl, ph, pl, rnorms, yi,
                                                                   fbuf, rowp, colp, b);
        rowcol_combine_kernel<<<dim3(16, 2),     256, 0, stream>>>(rowp, colp, rmax, rsuminv,
                                                                   coords, attn, cmax, csuminv, b);
        gemm_y_kernel        <<<dim3(64, 4),     512, 0, stream>>>(fbuf, rmax, yf16, yph, b);
        ycombine_kernel      <<<NCH*HW/256,      256, 0, stream>>>(yph, rsuminv, out, b);
        cyc_partial_kernel   <<<dim3(16, 32),    256, 0, stream>>>(fbuf, cmax, attn, cycp, b);
        cyc_combine_kernel   <<<dim3(16, 3),     256, 0, stream>>>(cycp, csuminv, cyc, b);
    }

    flow_kernel        <<<NB*2*65536/256, 256, 0, stream>>>(coords, out);
    imgout_kernel      <<<NB*3*65536/256, 256, 0, stream>>>(attn, cyc, out);
    loss_partial_kernel<<<1024,           256, 0, stream>>>(xf, yf, means, rnorms, lossp);
    loss_final_kernel  <<<1,              256, 0, stream>>>(lossp, out);
}

// Round 12
// 521.406 us; speedup vs baseline: 1.1347x; 1.0124x over previous
//
#include <hip/hip_runtime.h>
#include <math.h>

#define HW   4096
#define NCH  256
#define NB   4

constexpr float TEMP  = (float)(0.0001 * 5.0);
constexpr float INV_T = 1.0f / TEMP;
constexpr float EPSN  = 2.220446049250313e-16f;

typedef __attribute__((ext_vector_type(8))) _Float16 f16x8;
typedef __attribute__((ext_vector_type(4))) _Float16 f16x4;
typedef __attribute__((ext_vector_type(4))) float    f32x4;

// ---------------- workspace layout (in floats) ----------------
constexpr size_t OFF_YT    = 0;                                 // yf16: NB*HW*NCH f16
constexpr size_t OFF_YI    = OFF_YT    + (size_t)NB*HW*NCH;     // NB*3*HW
constexpr size_t OFF_MEAN  = OFF_YI    + (size_t)NB*3*HW;       // 2*NB*NCH
constexpr size_t OFF_RNORM = OFF_MEAN  + (size_t)2*NB*NCH;      // 2*NB*HW
constexpr size_t OFF_NSQP  = OFF_RNORM + (size_t)2*NB*HW;       // 2*NB*8*HW
constexpr size_t OFF_F     = OFF_NSQP  + (size_t)2*NB*8*HW;     // HW*HW (f32 f)
constexpr size_t OFF_YP    = OFF_F     + (size_t)HW*HW;         // region reused
// rowp/colp ALIAS the yp region: consumed by combine before gemm_y writes yph
constexpr size_t OFF_ROWP  = OFF_YP;                            // [32 ntile][7][HW]
constexpr size_t OFF_COLP  = OFF_YP + (size_t)32*7*HW;          // [32 mtile][1][HW] (max only)
constexpr size_t OFF_RMAX  = OFF_YP    + (size_t)8*NCH*HW;
constexpr size_t OFF_RSUM  = OFF_RMAX  + HW;
constexpr size_t OFF_CMAX  = OFF_RSUM  + HW;
constexpr size_t OFF_COORD = OFF_CMAX  + HW;                // NB*2*HW
constexpr size_t OFF_ATTN  = OFF_COORD + (size_t)NB*2*HW;   // NB*HW*3
constexpr size_t OFF_CYC   = OFF_ATTN  + (size_t)NB*HW*3;   // NB*3*HW
constexpr size_t OFF_CYCP  = OFF_CYC   + (size_t)NB*3*HW;   // 32*4*HW (3 attn + 1 denom)
constexpr size_t OFF_LOSSP = OFF_CYCP  + (size_t)32*4*HW;   // 1024
constexpr size_t OFF_F16   = OFF_LOSSP + 1024;              // 4 * 524288 floats

// ---------------- output layout (floats) ----------------
constexpr size_t OUT_Y    = 0;
constexpr size_t OUT_FLOW = (size_t)NB*NCH*HW;
constexpr size_t OUT_IMG  = OUT_FLOW + (size_t)NB*2*256*256;
constexpr size_t OUT_CYCO = OUT_IMG  + (size_t)NB*3*256*256;
constexpr size_t OUT_LOSS = OUT_CYCO + (size_t)NB*3*256*256;

__device__ __forceinline__ void gload16(const void* g, void* l) {
    __builtin_amdgcn_global_load_lds(
        (const __attribute__((address_space(1))) unsigned int*)g,
        (__attribute__((address_space(3))) unsigned int*)l, 16, 0, 0);
}

__global__ void mean_kernel(const float* __restrict__ xf, const float* __restrict__ yf,
                            float* __restrict__ means) {
    const float* src = (blockIdx.y == 0 ? xf : yf) + (size_t)blockIdx.x * HW;
    float s = 0.f;
    for (int i = threadIdx.x; i < HW; i += 256) s += src[i];
    __shared__ float red[256];
    red[threadIdx.x] = s; __syncthreads();
    for (int st = 128; st > 0; st >>= 1) {
        if (threadIdx.x < st) red[threadIdx.x] += red[threadIdx.x + st];
        __syncthreads();
    }
    if (threadIdx.x == 0) means[blockIdx.y * (NB*NCH) + blockIdx.x] = red[0] * (1.0f / HW);
}

// per-batch combine of nsq partials written by prep_kernel
__global__ void nsq_combine_kernel(const float* __restrict__ part, float* __restrict__ rnorms,
                                   int b) {
    int t = blockIdx.y;
    int m = blockIdx.x * 256 + threadIdx.x;
    const float* p = part + ((size_t)t*NB + b) * 8 * HW + m;
    float s = 0.f;
    for (int k = 0; k < 8; ++k) s += p[(size_t)k * HW];
    rnorms[((size_t)t*NB + b) * HW + m] = 1.0f / (sqrtf(s) + EPSN);
}

__global__ void ycast_kernel(const float* __restrict__ yf, _Float16* __restrict__ yf16) {
    size_t i = ((size_t)blockIdx.x * 256 + threadIdx.x) * 8;
    const float4* s = (const float4*)(yf + i);
    float4 v0 = s[0], v1 = s[1];
    f16x8 o;
    o[0]=(_Float16)v0.x; o[1]=(_Float16)v0.y; o[2]=(_Float16)v0.z; o[3]=(_Float16)v0.w;
    o[4]=(_Float16)v1.x; o[5]=(_Float16)v1.y; o[6]=(_Float16)v1.z; o[7]=(_Float16)v1.w;
    *(f16x8*)(yf16 + i) = o;
}

// centered hi/lo f16 split in transposed [m][c] layout + nsq partials (fused)
__global__ void prep_kernel(const float* __restrict__ xf, const float* __restrict__ yf,
                            const float* __restrict__ means,
                            _Float16* __restrict__ th, _Float16* __restrict__ tl,
                            _Float16* __restrict__ ph, _Float16* __restrict__ pl,
                            float* __restrict__ nsqp, int b) {
    __shared__ float tile[32][33];
    __shared__ float sqr[8][33];
    int t = blockIdx.z;
    int c0 = blockIdx.x * 32, m0 = blockIdx.y * 32;
    const float* src = (t == 0 ? xf : yf) + (size_t)b * NCH * HW;
    const float* mn  = means + t * (NB*NCH) + b * NCH;
    int tx = threadIdx.x & 31, ty = threadIdx.x >> 5;
    float sq = 0.f;
    for (int i = ty; i < 32; i += 8) {
        float v = src[(size_t)(c0 + i) * HW + m0 + tx] - mn[c0 + i];
        tile[i][tx] = v;
        sq += v * v;
    }
    sqr[ty][tx] = sq;
    __syncthreads();
    _Float16* H = (t == 0 ? th : ph);
    _Float16* L = (t == 0 ? tl : pl);
    for (int i = ty; i < 32; i += 8) {
        float v = tile[tx][i];
        _Float16 h = (_Float16)v;
        _Float16 l = (_Float16)(v - (float)h);
        H[(size_t)(m0 + i)*NCH + c0 + tx] = h;
        L[(size_t)(m0 + i)*NCH + c0 + tx] = l;
    }
    if (ty == 0) {
        float s = 0.f;
        #pragma unroll
        for (int k = 0; k < 8; ++k) s += sqr[k][tx];
        nsqp[(((size_t)t*NB + b) * 8 + blockIdx.x) * HW + m0 + tx] = s;
    }
}

__global__ void avgpool_kernel(const float* __restrict__ yimg, float* __restrict__ yi) {
    size_t idx = (size_t)blockIdx.x * 256 + threadIdx.x;
    int m  = (int)(idx & (HW - 1));
    int bc = (int)(idx >> 12);
    int h = m >> 6, w = m & 63;
    const float* p = yimg + (size_t)bc * 65536 + (size_t)(h*4) * 256 + w*4;
    float s = 0.f;
    #pragma unroll
    for (int dy = 0; dy < 4; ++dy) {
        #pragma unroll
        for (int dx = 0; dx < 4; ++dx) s += p[dy*256 + dx];
    }
    yi[idx] = s * (1.0f/16.0f);
}

// f^T accumulator GEMM: 128x128 tile, 4 waves, BK=32, 2-phase dbuf LDS.
// Stats epilogue: row max + 6 exp-weighted row sums; col MAX only (col exp-sums
// moved to cyc_partial, which already computes every exp((f-cmax)/T)).
__global__ __launch_bounds__(256) void gemm_f_kernel(
        const _Float16* __restrict__ th, const _Float16* __restrict__ tl,
        const _Float16* __restrict__ ph, const _Float16* __restrict__ pl,
        const float* __restrict__ rnorms, const float* __restrict__ yi,
        float* __restrict__ f, float* __restrict__ rowp, float* __restrict__ colp,
        int b) {
    __shared__ char lds[2][4][8192];
    int tid  = threadIdx.x;
    int lane = tid & 63;
    int w = tid >> 6, wm = w >> 1, wn = w & 1;   // wm: n-block, wn: m-block
    int m0 = blockIdx.y * 128, n0 = blockIdx.x * 128;

    int o0 = tid * 16, o1 = o0 + 4096;
    int r0 = o0 >> 6, s0 = (o0 >> 4) & 3, g0 = s0 ^ ((r0 >> 1) & 3);
    int r1 = o1 >> 6, s1 = (o1 >> 4) & 3, g1 = s1 ^ ((r1 >> 1) & 3);
    size_t ga0 = (size_t)(n0 + r0)*NCH + g0*8;
    size_t ga1 = (size_t)(n0 + r1)*NCH + g1*8;
    size_t gb0 = (size_t)(m0 + r0)*NCH + g0*8;
    size_t gb1 = (size_t)(m0 + r1)*NCH + g1*8;

    int fra = wm*64 + (lane & 15);
    int frb = wn*64 + (lane & 15);
    int ks  = lane >> 4;

    auto STAGE = [&](int buf, int k0) {
        gload16(ph + ga0 + k0, &lds[buf][0][o0]);
        gload16(ph + ga1 + k0, &lds[buf][0][o1]);
        gload16(pl + ga0 + k0, &lds[buf][1][o0]);
        gload16(pl + ga1 + k0, &lds[buf][1][o1]);
        gload16(th + gb0 + k0, &lds[buf][2][o0]);
        gload16(th + gb1 + k0, &lds[buf][2][o1]);
        gload16(tl + gb0 + k0, &lds[buf][3][o0]);
        gload16(tl + gb1 + k0, &lds[buf][3][o1]);
    };

    f32x4 acc[4][4];
    #pragma unroll
    for (int i = 0; i < 4; ++i)
        #pragma unroll
        for (int j = 0; j < 4; ++j) acc[i][j] = (f32x4){0.f, 0.f, 0.f, 0.f};

    STAGE(0, 0);
    __syncthreads();
    int cur = 0;
    for (int kt = 0; kt < 8; ++kt) {
        if (kt < 7) STAGE(cur ^ 1, (kt + 1) * 32);

        f16x8 ah[4], al[4], bh[4], bl[4];
        #pragma unroll
        for (int i = 0; i < 4; ++i) {
            int rowa = fra + i*16;
            int offa = rowa*64 + ((ks ^ ((rowa >> 1) & 3)) << 4);
            ah[i] = *(const f16x8*)&lds[cur][0][offa];
            al[i] = *(const f16x8*)&lds[cur][1][offa];
            int rowb = frb + i*16;
            int offb = rowb*64 + ((ks ^ ((rowb >> 1) & 3)) << 4);
            bh[i] = *(const f16x8*)&lds[cur][2][offb];
            bl[i] = *(const f16x8*)&lds[cur][3][offb];
        }
        __builtin_amdgcn_s_setprio(1);
        #pragma unroll
        for (int i = 0; i < 4; ++i)
            #pragma unroll
            for (int j = 0; j < 4; ++j) {
                acc[i][j] = __builtin_amdgcn_mfma_f32_16x16x32_f16(ah[i], bh[j], acc[i][j], 0, 0, 0);
                acc[i][j] = __builtin_amdgcn_mfma_f32_16x16x32_f16(ah[i], bl[j], acc[i][j], 0, 0, 0);
                acc[i][j] = __builtin_amdgcn_mfma_f32_16x16x32_f16(al[i], bh[j], acc[i][j], 0, 0, 0);
            }
        __builtin_amdgcn_s_setprio(0);
        __syncthreads();
        cur ^= 1;
    }

    // ---- scale in place: f[m][n] = accT * rnx[m] * rny[n] ----
    const float* rnx = rnorms + (size_t)b * HW;
    const float* rny = rnorms + (size_t)(NB + b) * HW;
    int mg[4];  float rxv[4];
    #pragma unroll
    for (int j = 0; j < 4; ++j) {
        mg[j] = m0 + wn*64 + j*16 + (lane & 15);
        rxv[j] = rnx[mg[j]];
    }
    int nl0 = wm*64 + (lane >> 4)*4;
    #pragma unroll
    for (int i = 0; i < 4; ++i)
        #pragma unroll
        for (int r = 0; r < 4; ++r) {
            float ry = rny[n0 + nl0 + i*16 + r];
            #pragma unroll
            for (int j = 0; j < 4; ++j) acc[i][j][r] *= rxv[j] * ry;
        }

    // ---- write f: one float4 per (i,j) ----
    #pragma unroll
    for (int j = 0; j < 4; ++j)
        #pragma unroll
        for (int i = 0; i < 4; ++i)
            *(f32x4*)&f[(size_t)mg[j]*HW + n0 + nl0 + i*16] = acc[i][j];

    // ---- stats (deterministic; LDS reuse after final loop barrier) ----
    float* S     = (float*)&lds[0][0][0];
    float* rowm  = S;          // [2 wm][128 m]
    float* sums6 = S + 256;    // [2 wm][128 m][6]
    float* colm  = S + 1792;   // [2 wn][128 n]

    // phase A: per-wave maxes
    #pragma unroll
    for (int j = 0; j < 4; ++j) {
        float v = acc[0][j][0];
        #pragma unroll
        for (int i = 0; i < 4; ++i)
            #pragma unroll
            for (int r = 0; r < 4; ++r) v = fmaxf(v, acc[i][j][r]);
        v = fmaxf(v, __shfl_xor(v, 16));
        v = fmaxf(v, __shfl_xor(v, 32));
        if ((lane >> 4) == 0) rowm[wm*128 + wn*64 + j*16 + lane] = v;
    }
    #pragma unroll
    for (int i = 0; i < 4; ++i)
        #pragma unroll
        for (int r = 0; r < 4; ++r) {
            float v = fmaxf(fmaxf(acc[i][0][r], acc[i][1][r]),
                            fmaxf(acc[i][2][r], acc[i][3][r]));
            #pragma unroll
            for (int d = 1; d < 16; d <<= 1) v = fmaxf(v, __shfl_xor(v, d));
            if ((lane & 15) == 0) colm[wn*128 + wm*64 + i*16 + (lane >> 4)*4 + r] = v;
        }
    __syncthreads();

    // phase B: row exp sums vs block maxes (col exp-sums live in cyc_partial now)
    float bm[4];
    #pragma unroll
    for (int j = 0; j < 4; ++j) {
        int ml = wn*64 + j*16 + (lane & 15);
        bm[j] = fmaxf(rowm[ml], rowm[128 + ml]);
    }
    float a6[4][6];
    #pragma unroll
    for (int j = 0; j < 4; ++j)
        #pragma unroll
        for (int q = 0; q < 6; ++q) a6[j][q] = 0.f;
    const float* yib = yi + (size_t)b * 3 * HW;
    #pragma unroll
    for (int i = 0; i < 4; ++i)
        #pragma unroll
        for (int r = 0; r < 4; ++r) {
            int ng = n0 + nl0 + i*16 + r;
            float xc = (float)(ng & 63), yc = (float)(ng >> 6);
            float y0 = yib[ng], y1 = yib[HW + ng], y2 = yib[2*HW + ng];
            #pragma unroll
            for (int j = 0; j < 4; ++j) {
                float e = __expf((acc[i][j][r] - bm[j]) * INV_T);
                a6[j][0] += e;      a6[j][1] += e*xc; a6[j][2] += e*yc;
                a6[j][3] += e*y0;   a6[j][4] += e*y1; a6[j][5] += e*y2;
            }
        }
    #pragma unroll
    for (int j = 0; j < 4; ++j)
        #pragma unroll
        for (int q = 0; q < 6; ++q) {
            float v = a6[j][q];
            v += __shfl_xor(v, 16);
            v += __shfl_xor(v, 32);
            if ((lane >> 4) == 0) sums6[(wm*128 + wn*64 + j*16 + lane)*6 + q] = v;
        }
    __syncthreads();

    // phase C: global partial writes
    if (tid < 128) {
        int ml = tid;
        float m2 = fmaxf(rowm[ml], rowm[128 + ml]);
        rowp[((size_t)blockIdx.x*7 + 0)*HW + m0 + ml] = m2;
        #pragma unroll
        for (int q = 0; q < 6; ++q)
            rowp[((size_t)blockIdx.x*7 + 1 + q)*HW + m0 + ml] =
                sums6[ml*6 + q] + sums6[(128 + ml)*6 + q];
    } else {
        int nl = tid - 128;
        colp[(size_t)blockIdx.y*HW + n0 + nl] = fmaxf(colm[nl], colm[128 + nl]);
    }
}

// merged combine: y==0 -> row stats; y==1 -> col max only
__global__ void rowcol_combine_kernel(const float* __restrict__ rowp,
        const float* __restrict__ colp,
        float* __restrict__ rmax, float* __restrict__ rsuminv,
        float* __restrict__ coords, float* __restrict__ attn,
        float* __restrict__ cmax, int b) {
    int idx = blockIdx.x * 256 + threadIdx.x;
    if (blockIdx.y == 0) {
        int m = idx;
        float gm = -3.0e38f;
        for (int t = 0; t < 32; ++t) gm = fmaxf(gm, rowp[((size_t)t*7)*HW + m]);
        float S=0, CX=0, CY=0, A0=0, A1=0, A2=0;
        for (int t = 0; t < 32; ++t) {
            const float* p = rowp + (size_t)t*7*HW + m;
            float wgt = __expf((p[0] - gm) * INV_T);
            S  += p[1*HW] * wgt; CX += p[2*HW] * wgt; CY += p[3*HW] * wgt;
            A0 += p[4*HW] * wgt; A1 += p[5*HW] * wgt; A2 += p[6*HW] * wgt;
        }
        float inv = 1.0f / S;
        rmax[m] = gm; rsuminv[m] = inv;
        coords[((size_t)b*2 + 0)*HW + m] = CX * inv;
        coords[((size_t)b*2 + 1)*HW + m] = CY * inv;
        attn[((size_t)b*HW + m)*3 + 0] = A0 * inv;
        attn[((size_t)b*HW + m)*3 + 1] = A1 * inv;
        attn[((size_t)b*HW + m)*3 + 2] = A2 * inv;
    } else {
        int n = idx;
        float gm = -3.0e38f;
        for (int t = 0; t < 32; ++t) gm = fmaxf(gm, colp[(size_t)t*HW + n]);
        cmax[n] = gm;
    }
}

// y partials: MFMA f16, split-K=4, tile 64m x 256c, 8 waves; f16 partial output.
// A-staging spread over all 512 threads (4 exps each).
__global__ __launch_bounds__(512) void gemm_y_kernel(const float* __restrict__ f,
        const float* __restrict__ rmax, const _Float16* __restrict__ yf16,
        _Float16* __restrict__ yph, int b) {
    __shared__ __align__(16) char ldsA[4096];    // P tile [64 m][32 k] f16
    __shared__ __align__(16) char ldsB[16384];   // Y tile [256 c][32 k] f16
    int tid  = threadIdx.x;
    int lane = tid & 63;
    int w = tid >> 6, wm = w >> 2, wn = w & 3;
    int m0 = blockIdx.x * 64;
    int ks = blockIdx.y;
    const _Float16* Yb = yf16 + (size_t)b * NCH * HW;

    // A staging: all 512 threads -> (row ar = tid>>3, 4-col chunk kc = tid&7)
    int ar = tid >> 3, kc = tid & 7;
    int aslot = kc >> 1, ahalf = kc & 1;
    int aoff = ar*64 + ((aslot ^ ((ar >> 1) & 3)) << 4) + ahalf*8;
    float arm = rmax[m0 + ar];
    const float* frow = f + (size_t)(m0 + ar)*HW + kc*4;

    int o0 = tid*16, o1 = o0 + 8192;
    int br0 = o0 >> 6, bs0 = (o0 >> 4) & 3, bg0 = bs0 ^ ((br0 >> 1) & 3);
    int br1 = o1 >> 6, bs1 = (o1 >> 4) & 3, bg1 = bs1 ^ ((br1 >> 1) & 3);
    size_t gb0 = (size_t)br0*HW + bg0*8;
    size_t gb1 = (size_t)br1*HW + bg1*8;

    int fra = wm*32 + (lane & 15);
    int frb = wn*64 + (lane & 15);
    int kslot = lane >> 4;

    f32x4 acc[2][4];
    #pragma unroll
    for (int i = 0; i < 2; ++i)
        #pragma unroll
        for (int j = 0; j < 4; ++j) acc[i][j] = (f32x4){0.f, 0.f, 0.f, 0.f};

    for (int k0 = ks*1024; k0 < ks*1024 + 1024; k0 += 32) {
        gload16(Yb + gb0 + k0, &ldsB[o0]);
        gload16(Yb + gb1 + k0, &ldsB[o1]);
        {
            float4 v = *(const float4*)(frow + k0);
            f16x4 pk;
            pk[0] = (_Float16)__expf((v.x - arm) * INV_T);
            pk[1] = (_Float16)__expf((v.y - arm) * INV_T);
            pk[2] = (_Float16)__expf((v.z - arm) * INV_T);
            pk[3] = (_Float16)__expf((v.w - arm) * INV_T);
            *(f16x4*)&ldsA[aoff] = pk;
        }
        __syncthreads();

        f16x8 af[2], bf[4];
        #pragma unroll
        for (int i = 0; i < 2; ++i) {
            int rowa = fra + i*16;
            af[i] = *(const f16x8*)&ldsA[rowa*64 + ((kslot ^ ((rowa >> 1) & 3)) << 4)];
        }
        #pragma unroll
        for (int j = 0; j < 4; ++j) {
            int rowb = frb + j*16;
            bf[j] = *(const f16x8*)&ldsB[rowb*64 + ((kslot ^ ((rowb >> 1) & 3)) << 4)];
        }
        __builtin_amdgcn_s_setprio(1);
        #pragma unroll
        for (int i = 0; i < 2; ++i)
            #pragma unroll
            for (int j = 0; j < 4; ++j)
                acc[i][j] = __builtin_amdgcn_mfma_f32_16x16x32_f16(af[i], bf[j], acc[i][j], 0, 0, 0);
        __builtin_amdgcn_s_setprio(0);
        __syncthreads();
    }

    #pragma unroll
    for (int i = 0; i < 2; ++i) {
        int m = m0 + wm*32 + i*16 + (lane >> 4) * 4;
        #pragma unroll
        for (int j = 0; j < 4; ++j) {
            int c = wn*64 + j*16 + (lane & 15);
            f16x4 v;
            #pragma unroll
            for (int r = 0; r < 4; ++r) v[r] = (_Float16)acc[i][j][r];
            *(f16x4*)(yph + ((size_t)ks*NCH + c)*HW + m) = v;
        }
    }
}

__global__ void ycombine_kernel(const _Float16* __restrict__ yph, const float* __restrict__ rsuminv,
                                float* __restrict__ out, int b) {
    size_t idx = (size_t)blockIdx.x * 256 + threadIdx.x;
    int m = (int)(idx & (HW - 1));
    float s = 0.f;
    #pragma unroll
    for (int k = 0; k < 4; ++k) s += (float)yph[(size_t)k*NCH*HW + idx];
    out[OUT_Y + (size_t)b*NCH*HW + idx] = s * rsuminv[m];
}

// cyc partial over row-chunks of 128; also emits col-denominator partial (ch 3)
__global__ __launch_bounds__(256) void cyc_partial_kernel(const float* __restrict__ f,
        const float* __restrict__ cmax, const float* __restrict__ attn,
        float* __restrict__ part, int b) {
    __shared__ float at[128*3];
    int i  = blockIdx.x * 256 + threadIdx.x;
    int j0 = blockIdx.y * 128;
    for (int k = threadIdx.x; k < 384; k += 256)
        at[k] = attn[((size_t)b*HW + j0)*3 + k];
    __syncthreads();
    float cm = cmax[i];
    float a0=0, a1=0, a2=0, a3=0;
    for (int jj = 0; jj < 128; ++jj) {
        float e = __expf((f[(size_t)(j0+jj)*HW + i] - cm) * INV_T);
        a0 = fmaf(e, at[jj*3+0], a0);
        a1 = fmaf(e, at[jj*3+1], a1);
        a2 = fmaf(e, at[jj*3+2], a2);
        a3 += e;
    }
    part[((size_t)blockIdx.y*4 + 0)*HW + i] = a0;
    part[((size_t)blockIdx.y*4 + 1)*HW + i] = a1;
    part[((size_t)blockIdx.y*4 + 2)*HW + i] = a2;
    part[((size_t)blockIdx.y*4 + 3)*HW + i] = a3;
}

__global__ void cyc_combine_kernel(const float* __restrict__ part,
                                   float* __restrict__ cyc, int b) {
    int i = blockIdx.x * 256 + threadIdx.x;
    int c = blockIdx.y;
    float s = 0.f, den = 0.f;
    for (int k = 0; k < 32; ++k) {
        s   += part[((size_t)k*4 + c)*HW + i];
        den += part[((size_t)k*4 + 3)*HW + i];
    }
    cyc[((size_t)b*3 + c)*HW + i] = s / den;
}

__global__ void flow_kernel(const float* __restrict__ coords, float* __restrict__ out) {
    size_t idx = (size_t)blockIdx.x * 256 + threadIdx.x;
    int x4 = (int)(idx & 255);
    int y4 = (int)((idx >> 8) & 255);
    int ch = (int)((idx >> 16) & 1);
    int b  = (int)(idx >> 17);
    int w = x4 >> 2, h = y4 >> 2;
    int m = h*64 + w;
    float c1 = coords[((size_t)b*2 + ch)*HW + m];
    float c0 = (ch == 0) ? (float)w : (float)h;
    out[OUT_FLOW + idx] = c1 - c0;
}

__global__ void imgout_kernel(const float* __restrict__ attn, const float* __restrict__ cyc,
                              float* __restrict__ out) {
    size_t idx = (size_t)blockIdx.x * 256 + threadIdx.x;
    int x4 = (int)(idx & 255);
    int y4 = (int)((idx >> 8) & 255);
    int rest = (int)(idx >> 16);
    int ch = rest % 3, b = rest / 3;
    int m = (y4 >> 2)*64 + (x4 >> 2);
    out[OUT_IMG  + idx] = attn[((size_t)b*HW + m)*3 + ch];
    out[OUT_CYCO + idx] = cyc[((size_t)b*3 + ch)*HW + m];
}

__global__ void loss_partial_kernel(const float* __restrict__ xf, const float* __restrict__ yf,
                                    const float* __restrict__ means, const float* __restrict__ rnorms,
                                    float* __restrict__ part) {
    __shared__ float red[256];
    size_t base = (size_t)blockIdx.x * 4096;
    float s = 0.f;
    for (int k = 0; k < 16; ++k) {
        size_t id = base + (size_t)k*256 + threadIdx.x;
        int m  = (int)(id & (HW - 1));
        int bc = (int)(id >> 12);
        int b  = bc >> 8;
        float th = (xf[id] - means[bc])          * rnorms[(size_t)b*HW + m];
        float ph = (yf[id] - means[NB*NCH + bc]) * rnorms[(size_t)(NB + b)*HW + m];
        s += fabsf(th - ph);
    }
    red[threadIdx.x] = s; __syncthreads();
    for (int st = 128; st > 0; st >>= 1) {
        if (threadIdx.x < st) red[threadIdx.x] += red[threadIdx.x + st];
        __syncthreads();
    }
    if (threadIdx.x == 0) part[blockIdx.x] = red[0];
}

__global__ void loss_final_kernel(const float* __restrict__ part, float* __restrict__ out) {
    __shared__ float red[256];
    float s = 0.f;
    for (int k = threadIdx.x; k < 1024; k += 256) s += part[k];
    red[threadIdx.x] = s; __syncthreads();
    for (int st = 128; st > 0; st >>= 1) {
        if (threadIdx.x < st) red[threadIdx.x] += red[threadIdx.x + st];
        __syncthreads();
    }
    if (threadIdx.x == 0) out[OUT_LOSS] = red[0] * (1.0f / 4194304.0f);
}

extern "C" void kernel_launch(void* const* d_in, const int* in_sizes, int n_in,
                              void* d_out, int out_size, void* d_ws, size_t ws_size,
                              hipStream_t stream) {
    (void)in_sizes; (void)n_in; (void)out_size; (void)ws_size;
    const float* xf   = (const float*)d_in[0];
    const float* yf   = (const float*)d_in[1];
    const float* yimg = (const float*)d_in[2];
    float* out = (float*)d_out;
    float* ws  = (float*)d_ws;

    _Float16* yf16 = (_Float16*)(ws + OFF_YT);
    float* yi      = ws + OFF_YI;
    float* means   = ws + OFF_MEAN;
    float* rnorms  = ws + OFF_RNORM;
    float* nsqp    = ws + OFF_NSQP;
    float* fbuf    = ws + OFF_F;
    _Float16* yph  = (_Float16*)(ws + OFF_YP);
    float* rowp    = ws + OFF_ROWP;
    float* colp    = ws + OFF_COLP;
    float* rmax    = ws + OFF_RMAX;
    float* rsuminv = ws + OFF_RSUM;
    float* cmax    = ws + OFF_CMAX;
    float* coords  = ws + OFF_COORD;
    float* attn    = ws + OFF_ATTN;
    float* cyc     = ws + OFF_CYC;
    float* cycp    = ws + OFF_CYCP;
    float* lossp   = ws + OFF_LOSSP;
    _Float16* th = (_Float16*)(ws + OFF_F16);
    _Float16* tl = th + (size_t)HW*NCH;
    _Float16* ph = tl + (size_t)HW*NCH;
    _Float16* pl = ph + (size_t)HW*NCH;

    mean_kernel        <<<dim3(NB*NCH, 2),   256, 0, stream>>>(xf, yf, means);
    ycast_kernel       <<<2048,              256, 0, stream>>>(yf, yf16);
    avgpool_kernel     <<<NB*3*HW/256,       256, 0, stream>>>(yimg, yi);

    for (int b = 0; b < NB; ++b) {
        prep_kernel          <<<dim3(8, 128, 2), 256, 0, stream>>>(xf, yf, means, th, tl, ph, pl,
                                                                   nsqp, b);
        nsq_combine_kernel   <<<dim3(16, 2),     256, 0, stream>>>(nsqp, rnorms, b);
        gemm_f_kernel        <<<dim3(32, 32),    256, 0, stream>>>(th, tl, ph, pl, rnorms, yi,
                                                                   fbuf, rowp, colp, b);
        rowcol_combine_kernel<<<dim3(16, 2),     256, 0, stream>>>(rowp, colp, rmax, rsuminv,
                                                                   coords, attn, cmax, b);
        gemm_y_kernel        <<<dim3(64, 4),     512, 0, stream>>>(fbuf, rmax, yf16, yph, b);
        ycombine_kernel      <<<NCH*HW/256,      256, 0, stream>>>(yph, rsuminv, out, b);
        cyc_partial_kernel   <<<dim3(16, 32),    256, 0, stream>>>(fbuf, cmax, attn, cycp, b);
        cyc_combine_kernel   <<<dim3(16, 3),     256, 0, stream>>>(cycp, cyc, b);
    }

    flow_kernel        <<<NB*2*65536/256, 256, 0, stream>>>(coords, out);
    imgout_kernel      <<<NB*3*65536/256, 256, 0, stream>>>(attn, cyc, out);
    loss_partial_kernel<<<1024,           256, 0, stream>>>(xf, yf, means, rnorms, lossp);
    loss_final_kernel  <<<1,              256, 0, stream>>>(lossp, out);
}

// Round 13
// 515.913 us; speedup vs baseline: 1.1467x; 1.0106x over previous
//
#include <hip/hip_runtime.h>
#include <math.h>

#define HW   4096
#define NCH  256
#define NB   4

constexpr float TEMP  = (float)(0.0001 * 5.0);
constexpr float INV_T = 1.0f / TEMP;
constexpr float EPSN  = 2.220446049250313e-16f;

typedef __attribute__((ext_vector_type(8))) _Float16 f16x8;
typedef __attribute__((ext_vector_type(4))) _Float16 f16x4;
typedef __attribute__((ext_vector_type(4))) float    f32x4;

// ---------------- workspace layout (in floats) ----------------
constexpr size_t OFF_YT    = 0;                                 // yf16: NB*HW*NCH f16
constexpr size_t OFF_YI    = OFF_YT    + (size_t)NB*HW*NCH;     // NB*3*HW
constexpr size_t OFF_MEAN  = OFF_YI    + (size_t)NB*3*HW;       // 2*NB*NCH
constexpr size_t OFF_RNORM = OFF_MEAN  + (size_t)2*NB*NCH;      // 2*NB*HW
constexpr size_t OFF_NSQP  = OFF_RNORM + (size_t)2*NB*HW;       // 2*NB*8*HW
constexpr size_t OFF_F     = OFF_NSQP  + (size_t)2*NB*8*HW;     // HW*HW (f32 f)
constexpr size_t OFF_YP    = OFF_F     + (size_t)HW*HW;         // region reused
constexpr size_t OFF_ROWP  = OFF_YP;                            // [32 ntile][7][HW]
constexpr size_t OFF_COLP  = OFF_YP + (size_t)32*7*HW;          // [32 mtile][1][HW] (max only)
constexpr size_t OFF_RMAX  = OFF_YP    + (size_t)8*NCH*HW;
constexpr size_t OFF_RSUM  = OFF_RMAX  + HW;
constexpr size_t OFF_CMAX  = OFF_RSUM  + HW;
constexpr size_t OFF_COORD = OFF_CMAX  + HW;                // NB*2*HW
constexpr size_t OFF_ATTN  = OFF_COORD + (size_t)NB*2*HW;   // NB*HW*3
constexpr size_t OFF_CYC   = OFF_ATTN  + (size_t)NB*HW*3;   // NB*3*HW
constexpr size_t OFF_CYCP  = OFF_CYC   + (size_t)NB*3*HW;   // 32*4*HW
constexpr size_t OFF_LOSSP = OFF_CYCP  + (size_t)32*4*HW;   // 1024
constexpr size_t OFF_F16   = OFF_LOSSP + 1024;              // 4 * 524288 floats

// ---------------- output layout (floats) ----------------
constexpr size_t OUT_Y    = 0;
constexpr size_t OUT_FLOW = (size_t)NB*NCH*HW;
constexpr size_t OUT_IMG  = OUT_FLOW + (size_t)NB*2*256*256;
constexpr size_t OUT_CYCO = OUT_IMG  + (size_t)NB*3*256*256;
constexpr size_t OUT_LOSS = OUT_CYCO + (size_t)NB*3*256*256;

__device__ __forceinline__ void gload16(const void* g, void* l) {
    __builtin_amdgcn_global_load_lds(
        (const __attribute__((address_space(1))) unsigned int*)g,
        (__attribute__((address_space(3))) unsigned int*)l, 16, 0, 0);
}

__global__ void mean_kernel(const float* __restrict__ xf, const float* __restrict__ yf,
                            float* __restrict__ means) {
    const float* src = (blockIdx.y == 0 ? xf : yf) + (size_t)blockIdx.x * HW;
    float s = 0.f;
    for (int i = threadIdx.x; i < HW; i += 256) s += src[i];
    __shared__ float red[256];
    red[threadIdx.x] = s; __syncthreads();
    for (int st = 128; st > 0; st >>= 1) {
        if (threadIdx.x < st) red[threadIdx.x] += red[threadIdx.x + st];
        __syncthreads();
    }
    if (threadIdx.x == 0) means[blockIdx.y * (NB*NCH) + blockIdx.x] = red[0] * (1.0f / HW);
}

__global__ void nsq_combine_kernel(const float* __restrict__ part, float* __restrict__ rnorms,
                                   int b) {
    int t = blockIdx.y;
    int m = blockIdx.x * 256 + threadIdx.x;
    const float* p = part + ((size_t)t*NB + b) * 8 * HW + m;
    float s = 0.f;
    for (int k = 0; k < 8; ++k) s += p[(size_t)k * HW];
    rnorms[((size_t)t*NB + b) * HW + m] = 1.0f / (sqrtf(s) + EPSN);
}

__global__ void ycast_kernel(const float* __restrict__ yf, _Float16* __restrict__ yf16) {
    size_t i = ((size_t)blockIdx.x * 256 + threadIdx.x) * 8;
    const float4* s = (const float4*)(yf + i);
    float4 v0 = s[0], v1 = s[1];
    f16x8 o;
    o[0]=(_Float16)v0.x; o[1]=(_Float16)v0.y; o[2]=(_Float16)v0.z; o[3]=(_Float16)v0.w;
    o[4]=(_Float16)v1.x; o[5]=(_Float16)v1.y; o[6]=(_Float16)v1.z; o[7]=(_Float16)v1.w;
    *(f16x8*)(yf16 + i) = o;
}

__global__ void prep_kernel(const float* __restrict__ xf, const float* __restrict__ yf,
                            const float* __restrict__ means,
                            _Float16* __restrict__ th, _Float16* __restrict__ tl,
                            _Float16* __restrict__ ph, _Float16* __restrict__ pl,
                            float* __restrict__ nsqp, int b) {
    __shared__ float tile[32][33];
    __shared__ float sqr[8][33];
    int t = blockIdx.z;
    int c0 = blockIdx.x * 32, m0 = blockIdx.y * 32;
    const float* src = (t == 0 ? xf : yf) + (size_t)b * NCH * HW;
    const float* mn  = means + t * (NB*NCH) + b * NCH;
    int tx = threadIdx.x & 31, ty = threadIdx.x >> 5;
    float sq = 0.f;
    for (int i = ty; i < 32; i += 8) {
        float v = src[(size_t)(c0 + i) * HW + m0 + tx] - mn[c0 + i];
        tile[i][tx] = v;
        sq += v * v;
    }
    sqr[ty][tx] = sq;
    __syncthreads();
    _Float16* H = (t == 0 ? th : ph);
    _Float16* L = (t == 0 ? tl : pl);
    for (int i = ty; i < 32; i += 8) {
        float v = tile[tx][i];
        _Float16 h = (_Float16)v;
        _Float16 l = (_Float16)(v - (float)h);
        H[(size_t)(m0 + i)*NCH + c0 + tx] = h;
        L[(size_t)(m0 + i)*NCH + c0 + tx] = l;
    }
    if (ty == 0) {
        float s = 0.f;
        #pragma unroll
        for (int k = 0; k < 8; ++k) s += sqr[k][tx];
        nsqp[(((size_t)t*NB + b) * 8 + blockIdx.x) * HW + m0 + tx] = s;
    }
}

__global__ void avgpool_kernel(const float* __restrict__ yimg, float* __restrict__ yi) {
    size_t idx = (size_t)blockIdx.x * 256 + threadIdx.x;
    int m  = (int)(idx & (HW - 1));
    int bc = (int)(idx >> 12);
    int h = m >> 6, w = m & 63;
    const float* p = yimg + (size_t)bc * 65536 + (size_t)(h*4) * 256 + w*4;
    float s = 0.f;
    #pragma unroll
    for (int dy = 0; dy < 4; ++dy) {
        #pragma unroll
        for (int dx = 0; dx < 4; ++dx) s += p[dy*256 + dx];
    }
    yi[idx] = s * (1.0f/16.0f);
}

// f^T accumulator GEMM: 128x128 tile, 8 waves (4 m-quarters x 2 n-halves), BK=32,
// 2-phase dbuf LDS. Row max + 6 exp row sums; col MAX only.
__global__ __launch_bounds__(512) void gemm_f_kernel(
        const _Float16* __restrict__ th, const _Float16* __restrict__ tl,
        const _Float16* __restrict__ ph, const _Float16* __restrict__ pl,
        const float* __restrict__ rnorms, const float* __restrict__ yi,
        float* __restrict__ f, float* __restrict__ rowp, float* __restrict__ colp,
        int b) {
    __shared__ char lds[2][4][8192];
    int tid  = threadIdx.x;
    int lane = tid & 63;
    int w = tid >> 6;
    int wm = w >> 2;       // 0..1  n-half (A/phi)
    int wn = w & 3;        // 0..3  m-quarter (B/theta)
    int m0 = blockIdx.y * 128, n0 = blockIdx.x * 128;

    // staging: each of 512 threads stages one 16B chunk in each of the 4 arrays
    int o0 = tid * 16;
    int r0 = o0 >> 6, s0 = (o0 >> 4) & 3, g0 = s0 ^ ((r0 >> 1) & 3);
    size_t ga0 = (size_t)(n0 + r0)*NCH + g0*8;   // phi row (n)
    size_t gb0 = (size_t)(m0 + r0)*NCH + g0*8;   // theta row (m)

    int fra = wm*64 + (lane & 15);   // A fragment rows (n-local), +i*16, i<4
    int frb = wn*32 + (lane & 15);   // B fragment rows (m-local), +j*16, j<2
    int ks  = lane >> 4;

    auto STAGE = [&](int buf, int k0) {
        gload16(ph + ga0 + k0, &lds[buf][0][o0]);
        gload16(pl + ga0 + k0, &lds[buf][1][o0]);
        gload16(th + gb0 + k0, &lds[buf][2][o0]);
        gload16(tl + gb0 + k0, &lds[buf][3][o0]);
    };

    f32x4 acc[4][2];
    #pragma unroll
    for (int i = 0; i < 4; ++i)
        #pragma unroll
        for (int j = 0; j < 2; ++j) acc[i][j] = (f32x4){0.f, 0.f, 0.f, 0.f};

    STAGE(0, 0);
    __syncthreads();
    int cur = 0;
    for (int kt = 0; kt < 8; ++kt) {
        if (kt < 7) STAGE(cur ^ 1, (kt + 1) * 32);

        f16x8 ah[4], al[4], bh[2], bl[2];
        #pragma unroll
        for (int i = 0; i < 4; ++i) {
            int rowa = fra + i*16;
            int offa = rowa*64 + ((ks ^ ((rowa >> 1) & 3)) << 4);
            ah[i] = *(const f16x8*)&lds[cur][0][offa];
            al[i] = *(const f16x8*)&lds[cur][1][offa];
        }
        #pragma unroll
        for (int j = 0; j < 2; ++j) {
            int rowb = frb + j*16;
            int offb = rowb*64 + ((ks ^ ((rowb >> 1) & 3)) << 4);
            bh[j] = *(const f16x8*)&lds[cur][2][offb];
            bl[j] = *(const f16x8*)&lds[cur][3][offb];
        }
        __builtin_amdgcn_s_setprio(1);
        #pragma unroll
        for (int i = 0; i < 4; ++i)
            #pragma unroll
            for (int j = 0; j < 2; ++j) {
                acc[i][j] = __builtin_amdgcn_mfma_f32_16x16x32_f16(ah[i], bh[j], acc[i][j], 0, 0, 0);
                acc[i][j] = __builtin_amdgcn_mfma_f32_16x16x32_f16(ah[i], bl[j], acc[i][j], 0, 0, 0);
                acc[i][j] = __builtin_amdgcn_mfma_f32_16x16x32_f16(al[i], bh[j], acc[i][j], 0, 0, 0);
            }
        __builtin_amdgcn_s_setprio(0);
        __syncthreads();
        cur ^= 1;
    }

    // ---- scale in place: f[m][n] = accT * rnx[m] * rny[n] ----
    const float* rnx = rnorms + (size_t)b * HW;
    const float* rny = rnorms + (size_t)(NB + b) * HW;
    int mg[2];  float rxv[2];
    #pragma unroll
    for (int j = 0; j < 2; ++j) {
        mg[j] = m0 + wn*32 + j*16 + (lane & 15);
        rxv[j] = rnx[mg[j]];
    }
    int nl0 = wm*64 + (lane >> 4)*4;
    #pragma unroll
    for (int i = 0; i < 4; ++i)
        #pragma unroll
        for (int r = 0; r < 4; ++r) {
            float ry = rny[n0 + nl0 + i*16 + r];
            #pragma unroll
            for (int j = 0; j < 2; ++j) acc[i][j][r] *= rxv[j] * ry;
        }

    // ---- write f ----
    #pragma unroll
    for (int j = 0; j < 2; ++j)
        #pragma unroll
        for (int i = 0; i < 4; ++i)
            *(f32x4*)&f[(size_t)mg[j]*HW + n0 + nl0 + i*16] = acc[i][j];

    // ---- stats ----
    float* S     = (float*)&lds[0][0][0];
    float* rowm  = S;          // [2 wm][128 m]
    float* sums6 = S + 256;    // [2 wm][128 m][6]
    float* colm  = S + 1792;   // [4 wn][128 n]

    // phase A: per-wave maxes
    #pragma unroll
    for (int j = 0; j < 2; ++j) {
        float v = acc[0][j][0];
        #pragma unroll
        for (int i = 0; i < 4; ++i)
            #pragma unroll
            for (int r = 0; r < 4; ++r) v = fmaxf(v, acc[i][j][r]);
        v = fmaxf(v, __shfl_xor(v, 16));
        v = fmaxf(v, __shfl_xor(v, 32));
        if (lane < 16) rowm[wm*128 + wn*32 + j*16 + lane] = v;
    }
    #pragma unroll
    for (int i = 0; i < 4; ++i)
        #pragma unroll
        for (int r = 0; r < 4; ++r) {
            float v = fmaxf(acc[i][0][r], acc[i][1][r]);
            #pragma unroll
            for (int d = 1; d < 16; d <<= 1) v = fmaxf(v, __shfl_xor(v, d));
            if ((lane & 15) == 0) colm[wn*128 + nl0 + i*16 + r] = v;
        }
    __syncthreads();

    // phase B: row exp sums vs block maxes
    float bm[2];
    #pragma unroll
    for (int j = 0; j < 2; ++j) {
        int ml = wn*32 + j*16 + (lane & 15);
        bm[j] = fmaxf(rowm[ml], rowm[128 + ml]);
    }
    float a6[2][6];
    #pragma unroll
    for (int j = 0; j < 2; ++j)
        #pragma unroll
        for (int q = 0; q < 6; ++q) a6[j][q] = 0.f;
    const float* yib = yi + (size_t)b * 3 * HW;
    #pragma unroll
    for (int i = 0; i < 4; ++i)
        #pragma unroll
        for (int r = 0; r < 4; ++r) {
            int ng = n0 + nl0 + i*16 + r;
            float xc = (float)(ng & 63), yc = (float)(ng >> 6);
            float y0 = yib[ng], y1 = yib[HW + ng], y2 = yib[2*HW + ng];
            #pragma unroll
            for (int j = 0; j < 2; ++j) {
                float e = __expf((acc[i][j][r] - bm[j]) * INV_T);
                a6[j][0] += e;      a6[j][1] += e*xc; a6[j][2] += e*yc;
                a6[j][3] += e*y0;   a6[j][4] += e*y1; a6[j][5] += e*y2;
            }
        }
    #pragma unroll
    for (int j = 0; j < 2; ++j)
        #pragma unroll
        for (int q = 0; q < 6; ++q) {
            float v = a6[j][q];
            v += __shfl_xor(v, 16);
            v += __shfl_xor(v, 32);
            if (lane < 16) sums6[(wm*128 + wn*32 + j*16 + lane)*6 + q] = v;
        }
    __syncthreads();

    // phase C: global partial writes
    if (tid < 128) {
        int ml = tid;
        float m2 = fmaxf(rowm[ml], rowm[128 + ml]);
        rowp[((size_t)blockIdx.x*7 + 0)*HW + m0 + ml] = m2;
        #pragma unroll
        for (int q = 0; q < 6; ++q)
            rowp[((size_t)blockIdx.x*7 + 1 + q)*HW + m0 + ml] =
                sums6[ml*6 + q] + sums6[(128 + ml)*6 + q];
    } else if (tid < 256) {
        int nl = tid - 128;
        float c2 = fmaxf(fmaxf(colm[nl], colm[128 + nl]),
                         fmaxf(colm[256 + nl], colm[384 + nl]));
        colp[(size_t)blockIdx.y*HW + n0 + nl] = c2;
    }
}

// merged combine: y==0 -> row stats; y==1 -> col max only
__global__ void rowcol_combine_kernel(const float* __restrict__ rowp,
        const float* __restrict__ colp,
        float* __restrict__ rmax, float* __restrict__ rsuminv,
        float* __restrict__ coords, float* __restrict__ attn,
        float* __restrict__ cmax, int b) {
    int idx = blockIdx.x * 256 + threadIdx.x;
    if (blockIdx.y == 0) {
        int m = idx;
        float gm = -3.0e38f;
        for (int t = 0; t < 32; ++t) gm = fmaxf(gm, rowp[((size_t)t*7)*HW + m]);
        float S=0, CX=0, CY=0, A0=0, A1=0, A2=0;
        for (int t = 0; t < 32; ++t) {
            const float* p = rowp + (size_t)t*7*HW + m;
            float wgt = __expf((p[0] - gm) * INV_T);
            S  += p[1*HW] * wgt; CX += p[2*HW] * wgt; CY += p[3*HW] * wgt;
            A0 += p[4*HW] * wgt; A1 += p[5*HW] * wgt; A2 += p[6*HW] * wgt;
        }
        float inv = 1.0f / S;
        rmax[m] = gm; rsuminv[m] = inv;
        coords[((size_t)b*2 + 0)*HW + m] = CX * inv;
        coords[((size_t)b*2 + 1)*HW + m] = CY * inv;
        attn[((size_t)b*HW + m)*3 + 0] = A0 * inv;
        attn[((size_t)b*HW + m)*3 + 1] = A1 * inv;
        attn[((size_t)b*HW + m)*3 + 2] = A2 * inv;
    } else {
        int n = idx;
        float gm = -3.0e38f;
        for (int t = 0; t < 32; ++t) gm = fmaxf(gm, colp[(size_t)t*HW + n]);
        cmax[n] = gm;
    }
}

// y partials: MFMA f16, split-K=4, tile 64m x 256c, 8 waves; f16 partial output.
__global__ __launch_bounds__(512) void gemm_y_kernel(const float* __restrict__ f,
        const float* __restrict__ rmax, const _Float16* __restrict__ yf16,
        _Float16* __restrict__ yph, int b) {
    __shared__ __align__(16) char ldsA[4096];
    __shared__ __align__(16) char ldsB[16384];
    int tid  = threadIdx.x;
    int lane = tid & 63;
    int w = tid >> 6, wm = w >> 2, wn = w & 3;
    int m0 = blockIdx.x * 64;
    int ks = blockIdx.y;
    const _Float16* Yb = yf16 + (size_t)b * NCH * HW;

    int ar = tid >> 3, kc = tid & 7;
    int aslot = kc >> 1, ahalf = kc & 1;
    int aoff = ar*64 + ((aslot ^ ((ar >> 1) & 3)) << 4) + ahalf*8;
    float arm = rmax[m0 + ar];
    const float* frow = f + (size_t)(m0 + ar)*HW + kc*4;

    int o0 = tid*16, o1 = o0 + 8192;
    int br0 = o0 >> 6, bs0 = (o0 >> 4) & 3, bg0 = bs0 ^ ((br0 >> 1) & 3);
    int br1 = o1 >> 6, bs1 = (o1 >> 4) & 3, bg1 = bs1 ^ ((br1 >> 1) & 3);
    size_t gb0 = (size_t)br0*HW + bg0*8;
    size_t gb1 = (size_t)br1*HW + bg1*8;

    int fra = wm*32 + (lane & 15);
    int frb = wn*64 + (lane & 15);
    int kslot = lane >> 4;

    f32x4 acc[2][4];
    #pragma unroll
    for (int i = 0; i < 2; ++i)
        #pragma unroll
        for (int j = 0; j < 4; ++j) acc[i][j] = (f32x4){0.f, 0.f, 0.f, 0.f};

    for (int k0 = ks*1024; k0 < ks*1024 + 1024; k0 += 32) {
        gload16(Yb + gb0 + k0, &ldsB[o0]);
        gload16(Yb + gb1 + k0, &ldsB[o1]);
        {
            float4 v = *(const float4*)(frow + k0);
            f16x4 pk;
            pk[0] = (_Float16)__expf((v.x - arm) * INV_T);
            pk[1] = (_Float16)__expf((v.y - arm) * INV_T);
            pk[2] = (_Float16)__expf((v.z - arm) * INV_T);
            pk[3] = (_Float16)__expf((v.w - arm) * INV_T);
            *(f16x4*)&ldsA[aoff] = pk;
        }
        __syncthreads();

        f16x8 af[2], bf[4];
        #pragma unroll
        for (int i = 0; i < 2; ++i) {
            int rowa = fra + i*16;
            af[i] = *(const f16x8*)&ldsA[rowa*64 + ((kslot ^ ((rowa >> 1) & 3)) << 4)];
        }
        #pragma unroll
        for (int j = 0; j < 4; ++j) {
            int rowb = frb + j*16;
            bf[j] = *(const f16x8*)&ldsB[rowb*64 + ((kslot ^ ((rowb >> 1) & 3)) << 4)];
        }
        __builtin_amdgcn_s_setprio(1);
        #pragma unroll
        for (int i = 0; i < 2; ++i)
            #pragma unroll
            for (int j = 0; j < 4; ++j)
                acc[i][j] = __builtin_amdgcn_mfma_f32_16x16x32_f16(af[i], bf[j], acc[i][j], 0, 0, 0);
        __builtin_amdgcn_s_setprio(0);
        __syncthreads();
    }

    #pragma unroll
    for (int i = 0; i < 2; ++i) {
        int m = m0 + wm*32 + i*16 + (lane >> 4) * 4;
        #pragma unroll
        for (int j = 0; j < 4; ++j) {
            int c = wn*64 + j*16 + (lane & 15);
            f16x4 v;
            #pragma unroll
            for (int r = 0; r < 4; ++r) v[r] = (_Float16)acc[i][j][r];
            *(f16x4*)(yph + ((size_t)ks*NCH + c)*HW + m) = v;
        }
    }
}

__global__ void ycombine_kernel(const _Float16* __restrict__ yph, const float* __restrict__ rsuminv,
                                float* __restrict__ out, int b) {
    size_t idx = (size_t)blockIdx.x * 256 + threadIdx.x;
    int m = (int)(idx & (HW - 1));
    float s = 0.f;
    #pragma unroll
    for (int k = 0; k < 4; ++k) s += (float)yph[(size_t)k*NCH*HW + idx];
    out[OUT_Y + (size_t)b*NCH*HW + idx] = s * rsuminv[m];
}

__global__ __launch_bounds__(256) void cyc_partial_kernel(const float* __restrict__ f,
        const float* __restrict__ cmax, const float* __restrict__ attn,
        float* __restrict__ part, int b) {
    __shared__ float at[128*3];
    int i  = blockIdx.x * 256 + threadIdx.x;
    int j0 = blockIdx.y * 128;
    for (int k = threadIdx.x; k < 384; k += 256)
        at[k] = attn[((size_t)b*HW + j0)*3 + k];
    __syncthreads();
    float cm = cmax[i];
    float a0=0, a1=0, a2=0, a3=0;
    for (int jj = 0; jj < 128; ++jj) {
        float e = __expf((f[(size_t)(j0+jj)*HW + i] - cm) * INV_T);
        a0 = fmaf(e, at[jj*3+0], a0);
        a1 = fmaf(e, at[jj*3+1], a1);
        a2 = fmaf(e, at[jj*3+2], a2);
        a3 += e;
    }
    part[((size_t)blockIdx.y*4 + 0)*HW + i] = a0;
    part[((size_t)blockIdx.y*4 + 1)*HW + i] = a1;
    part[((size_t)blockIdx.y*4 + 2)*HW + i] = a2;
    part[((size_t)blockIdx.y*4 + 3)*HW + i] = a3;
}

__global__ void cyc_combine_kernel(const float* __restrict__ part,
                                   float* __restrict__ cyc, int b) {
    int i = blockIdx.x * 256 + threadIdx.x;
    int c = blockIdx.y;
    float s = 0.f, den = 0.f;
    for (int k = 0; k < 32; ++k) {
        s   += part[((size_t)k*4 + c)*HW + i];
        den += part[((size_t)k*4 + 3)*HW + i];
    }
    cyc[((size_t)b*3 + c)*HW + i] = s / den;
}

__global__ void flow_kernel(const float* __restrict__ coords, float* __restrict__ out) {
    size_t idx = (size_t)blockIdx.x * 256 + threadIdx.x;
    int x4 = (int)(idx & 255);
    int y4 = (int)((idx >> 8) & 255);
    int ch = (int)((idx >> 16) & 1);
    int b  = (int)(idx >> 17);
    int w = x4 >> 2, h = y4 >> 2;
    int m = h*64 + w;
    float c1 = coords[((size_t)b*2 + ch)*HW + m];
    float c0 = (ch == 0) ? (float)w : (float)h;
    out[OUT_FLOW + idx] = c1 - c0;
}

__global__ void imgout_kernel(const float* __restrict__ attn, const float* __restrict__ cyc,
                              float* __restrict__ out) {
    size_t idx = (size_t)blockIdx.x * 256 + threadIdx.x;
    int x4 = (int)(idx & 255);
    int y4 = (int)((idx >> 8) & 255);
    int rest = (int)(idx >> 16);
    int ch = rest % 3, b = rest / 3;
    int m = (y4 >> 2)*64 + (x4 >> 2);
    out[OUT_IMG  + idx] = attn[((size_t)b*HW + m)*3 + ch];
    out[OUT_CYCO + idx] = cyc[((size_t)b*3 + ch)*HW + m];
}

__global__ void loss_partial_kernel(const float* __restrict__ xf, const float* __restrict__ yf,
                                    const float* __restrict__ means, const float* __restrict__ rnorms,
                                    float* __restrict__ part) {
    __shared__ float red[256];
    size_t base = (size_t)blockIdx.x * 4096;
    float s = 0.f;
    for (int k = 0; k < 16; ++k) {
        size_t id = base + (size_t)k*256 + threadIdx.x;
        int m  = (int)(id & (HW - 1));
        int bc = (int)(id >> 12);
        int b  = bc >> 8;
        float th = (xf[id] - means[bc])          * rnorms[(size_t)b*HW + m];
        float ph = (yf[id] - means[NB*NCH + bc]) * rnorms[(size_t)(NB + b)*HW + m];
        s += fabsf(th - ph);
    }
    red[threadIdx.x] = s; __syncthreads();
    for (int st = 128; st > 0; st >>= 1) {
        if (threadIdx.x < st) red[threadIdx.x] += red[threadIdx.x + st];
        __syncthreads();
    }
    if (threadIdx.x == 0) part[blockIdx.x] = red[0];
}

__global__ void loss_final_kernel(const float* __restrict__ part, float* __restrict__ out) {
    __shared__ float red[256];
    float s = 0.f;
    for (int k = threadIdx.x; k < 1024; k += 256) s += part[k];
    red[threadIdx.x] = s; __syncthreads();
    for (int st = 128; st > 0; st >>= 1) {
        if (threadIdx.x < st) red[threadIdx.x] += red[threadIdx.x + st];
        __syncthreads();
    }
    if (threadIdx.x == 0) out[OUT_LOSS] = red[0] * (1.0f / 4194304.0f);
}

extern "C" void kernel_launch(void* const* d_in, const int* in_sizes, int n_in,
                              void* d_out, int out_size, void* d_ws, size_t ws_size,
                              hipStream_t stream) {
    (void)in_sizes; (void)n_in; (void)out_size; (void)ws_size;
    const float* xf   = (const float*)d_in[0];
    const float* yf   = (const float*)d_in[1];
    const float* yimg = (const float*)d_in[2];
    float* out = (float*)d_out;
    float* ws  = (float*)d_ws;

    _Float16* yf16 = (_Float16*)(ws + OFF_YT);
    float* yi      = ws + OFF_YI;
    float* means   = ws + OFF_MEAN;
    float* rnorms  = ws + OFF_RNORM;
    float* nsqp    = ws + OFF_NSQP;
    float* fbuf    = ws + OFF_F;
    _Float16* yph  = (_Float16*)(ws + OFF_YP);
    float* rowp    = ws + OFF_ROWP;
    float* colp    = ws + OFF_COLP;
    float* rmax    = ws + OFF_RMAX;
    float* rsuminv = ws + OFF_RSUM;
    float* cmax    = ws + OFF_CMAX;
    float* coords  = ws + OFF_COORD;
    float* attn    = ws + OFF_ATTN;
    float* cyc     = ws + OFF_CYC;
    float* cycp    = ws + OFF_CYCP;
    float* lossp   = ws + OFF_LOSSP;
    _Float16* th = (_Float16*)(ws + OFF_F16);
    _Float16* tl = th + (size_t)HW*NCH;
    _Float16* ph = tl + (size_t)HW*NCH;
    _Float16* pl = ph + (size_t)HW*NCH;

    mean_kernel        <<<dim3(NB*NCH, 2),   256, 0, stream>>>(xf, yf, means);
    ycast_kernel       <<<2048,              256, 0, stream>>>(yf, yf16);
    avgpool_kernel     <<<NB*3*HW/256,       256, 0, stream>>>(yimg, yi);

    for (int b = 0; b < NB; ++b) {
        prep_kernel          <<<dim3(8, 128, 2), 256, 0, stream>>>(xf, yf, means, th, tl, ph, pl,
                                                                   nsqp, b);
        nsq_combine_kernel   <<<dim3(16, 2),     256, 0, stream>>>(nsqp, rnorms, b);
        gemm_f_kernel        <<<dim3(32, 32),    512, 0, stream>>>(th, tl, ph, pl, rnorms, yi,
                                                                   fbuf, rowp, colp, b);
        rowcol_combine_kernel<<<dim3(16, 2),     256, 0, stream>>>(rowp, colp, rmax, rsuminv,
                                                                   coords, attn, cmax, b);
        gemm_y_kernel        <<<dim3(64, 4),     512, 0, stream>>>(fbuf, rmax, yf16, yph, b);
        ycombine_kernel      <<<NCH*HW/256,      256, 0, stream>>>(yph, rsuminv, out, b);
        cyc_partial_kernel   <<<dim3(16, 32),    256, 0, stream>>>(fbuf, cmax, attn, cycp, b);
        cyc_combine_kernel   <<<dim3(16, 3),     256, 0, stream>>>(cycp, cyc, b);
    }

    flow_kernel        <<<NB*2*65536/256, 256, 0, stream>>>(coords, out);
    imgout_kernel      <<<NB*3*65536/256, 256, 0, stream>>>(attn, cyc, out);
    loss_partial_kernel<<<1024,           256, 0, stream>>>(xf, yf, means, rnorms, lossp);
    loss_final_kernel  <<<1,              256, 0, stream>>>(lossp, out);
}